// Round 16
// baseline (29258.188 us; speedup 1.0000x reference)
//
#include <hip/hip_runtime.h>
#include <hip/hip_bf16.h>

typedef _Float16 f16x8 __attribute__((ext_vector_type(8)));
typedef float f32x4 __attribute__((ext_vector_type(4)));
typedef unsigned long long u64;

#define B_   128
#define T_   1024
#define H_   512
#define P_   32
#define HC_  16
#define MB_  32
#define NC_  8
#define NW_  4
#define SPIN_BOUND (1 << 20)
#define MIMIC_R 1024            // appended full-step replica rounds (bisection #2)

#define FRAG_MT 8192

// ws layout (bytes)
#define WS_HEXHI  0ull
#define WS_HEXLO  524288ull
#define WS_FLAGR  1048576ull
#define WS_FLAGX  1081344ull
#define WS_XCC    1097728ull
#define WS_MECH   1098752ull
#define WS_PROBE  1099776ull
#define WS_ZEROL  1100800ull
#define WS_XT     1100800ull
#define WS_HLAST  2673664ull
#define WS_H1HI   2935808ull
#define WS_H1LO   137153536ull
#define WS_NEED_SMALL 137153536ull
#define WS_NEED_FULL  271371264ull

#define MFMA(a, b, c) __builtin_amdgcn_mfma_f32_16x16x32_f16((a), (b), (c), 0, 0, 0)

#define LD16C(FLAGS, D, DB, P0, P1, P2, P3)                                     \
    asm volatile(                                                               \
        "global_load_dwordx4 %0, %16, off " FLAGS "\n\t"                        \
        "global_load_dwordx4 %1, %16, off offset:1024 " FLAGS "\n\t"            \
        "global_load_dwordx4 %2, %16, off offset:2048 " FLAGS "\n\t"            \
        "global_load_dwordx4 %3, %16, off offset:3072 " FLAGS "\n\t"            \
        "global_load_dwordx4 %4, %17, off " FLAGS "\n\t"                        \
        "global_load_dwordx4 %5, %17, off offset:1024 " FLAGS "\n\t"            \
        "global_load_dwordx4 %6, %17, off offset:2048 " FLAGS "\n\t"            \
        "global_load_dwordx4 %7, %17, off offset:3072 " FLAGS "\n\t"            \
        "global_load_dwordx4 %8, %18, off " FLAGS "\n\t"                        \
        "global_load_dwordx4 %9, %18, off offset:1024 " FLAGS "\n\t"            \
        "global_load_dwordx4 %10, %18, off offset:2048 " FLAGS "\n\t"           \
        "global_load_dwordx4 %11, %18, off offset:3072 " FLAGS "\n\t"           \
        "global_load_dwordx4 %12, %19, off " FLAGS "\n\t"                       \
        "global_load_dwordx4 %13, %19, off offset:1024 " FLAGS "\n\t"           \
        "global_load_dwordx4 %14, %19, off offset:2048 " FLAGS "\n\t"           \
        "global_load_dwordx4 %15, %19, off offset:3072 " FLAGS "\n\t"           \
        "s_waitcnt vmcnt(0)"                                                    \
        : "=&v"(D[0][0]), "=&v"(D[1][0]), "=&v"(D[2][0]), "=&v"(D[3][0]),       \
          "=&v"(D[0][1]), "=&v"(D[1][1]), "=&v"(D[2][1]), "=&v"(D[3][1]),       \
          "=&v"(DB[0][0]), "=&v"(DB[1][0]), "=&v"(DB[2][0]), "=&v"(DB[3][0]),   \
          "=&v"(DB[0][1]), "=&v"(DB[1][1]), "=&v"(DB[2][1]), "=&v"(DB[3][1])    \
        : "v"(P0), "v"(P1), "v"(P2), "v"(P3)                                    \
        : "memory")

__device__ __forceinline__ unsigned ald4(const unsigned* p) {
    return __hip_atomic_load(p, __ATOMIC_RELAXED, __HIP_MEMORY_SCOPE_AGENT);
}
__device__ __forceinline__ void ast4(void* p, unsigned v) {
    __hip_atomic_store((unsigned*)p, v, __ATOMIC_RELAXED, __HIP_MEMORY_SCOPE_AGENT);
}
__device__ __forceinline__ void st4_plain(unsigned* p, unsigned v) {
    asm volatile("global_store_dword %0, %1, off" :: "v"(p), "v"(v) : "memory");
}
__device__ __forceinline__ unsigned ld4_sc1(const unsigned* p) {
    unsigned r;
    asm volatile("global_load_dword %0, %1, off sc1\n\ts_waitcnt vmcnt(0)"
                 : "=v"(r) : "v"(p) : "memory");
    return r;
}
__device__ __forceinline__ unsigned short f16bits(_Float16 h) {
    union { _Float16 f; unsigned short s; } u; u.f = h; return u.s;
}
__device__ __forceinline__ void heat(unsigned v) {
    float a = (float)(v & 7u) + 1.0f;
    #pragma unroll
    for (int i = 0; i < 16; ++i)
        asm volatile("v_fmac_f32 %0, %1, %2" : "+v"(a) : "v"(1.000001f), "v"(a));
    asm volatile("" :: "v"(a));
}
__device__ __forceinline__ int gidx(int q, int row, int col) {
    return q * 512 + ((row * 16 + col) ^ (((row >> 2) & 1) << 4));
}

__global__ __launch_bounds__(256)
void xt_kernel(const float* __restrict__ x, float* __restrict__ xT) {
    int idx = blockIdx.x * 256 + threadIdx.x;
    if (idx < B_ * T_ * 3) {
        int d = idx % 3, rest = idx / 3;
        int t = rest % T_, b = rest / T_;
        xT[((size_t)t * B_ + b) * 3 + d] = x[idx];
    }
}

__global__ __launch_bounds__(256, 1)
void fused_slstm(const float* __restrict__ xT,
                 const float* __restrict__ W0, const float* __restrict__ R0,
                 const float* __restrict__ b0v,
                 const float* __restrict__ W1, const float* __restrict__ R1,
                 const float* __restrict__ b1v,
                 _Float16* __restrict__ hexFhi, _Float16* __restrict__ hexFlo,
                 unsigned* __restrict__ flagR, unsigned* __restrict__ flagX,
                 unsigned* __restrict__ xccbuf, unsigned* __restrict__ mech,
                 unsigned* __restrict__ probe,
                 _Float16* __restrict__ h1Fhi, _Float16* __restrict__ h1Flo,
                 float* __restrict__ hlast, int useH1Lo)
{
    constexpr int LDSH = 4 * 16 * 64 * 8;
    __shared__ _Float16 lds[2 * LDSH];
    __shared__ float gbuf[4 * 512];
    __shared__ int verdLds, mechLds, fastLds;

    const int tid  = threadIdx.x;
    const int lane = tid & 63;
    const int wid  = tid >> 6;
    const int l15  = lane & 15;
    const int l4   = lane >> 4;
    const int kg8  = l4 * 8;
    const int c    = blockIdx.x & 7;
    const int p    = blockIdx.x >> 3;
    const bool isL2 = (c >= 4);
    const int g    = c & 3;
    const int b0g  = g * MB_;

    const float* Rg  = isL2 ? R1 : R0;
    const float* bgp = isL2 ? b1v : b0v;

    // ---- stage weights ----
    {
        const int q = wid;
        const int grow = q * H_ + p * HC_ + l15;
        const float* rsrc = Rg + (size_t)grow * H_ + kg8;
        for (int kt = 0; kt < 16; ++kt) {
            const float* s = rsrc + kt * 32;
            _Float16* dhi = &lds[((q * 16 + kt) * 64 + lane) * 8];
            _Float16* dlo = dhi + LDSH;
            if (!isL2) {
                #pragma unroll
                for (int j = 0; j < 8; ++j) {
                    float v = s[j];
                    _Float16 h = (_Float16)v;
                    dhi[j] = h;
                    dlo[j] = (_Float16)(v - (float)h);
                }
            } else {
                const float* ws2 = W1 + (size_t)grow * H_ + kt * 32 + kg8;
                #pragma unroll
                for (int j = 0; j < 8; ++j) {
                    dhi[j] = (_Float16)s[j];
                    dlo[j] = (_Float16)ws2[j];
                }
            }
        }
    }

    // ==== Phase 1: XCC mapping verdict ====
    {
        unsigned myxcc;
        asm volatile("s_getreg_b32 %0, hwreg(20, 0, 32)" : "=s"(myxcc));
        if (tid == 0) ast4(xccbuf + blockIdx.x, 0x100u | (myxcc & 0xFFu));
        if (wid == 0) {
            const unsigned* xp = xccbuf + ((lane & 31) * 8 + c);
            unsigned v = 0;
            int ok = 0;
            for (int it = 0; it < SPIN_BOUND; ++it) {
                v = ald4(xp);
                if (__ballot(v >= 0x100u) == ~0ull) { ok = 1; break; }
                __builtin_amdgcn_s_sleep(2);
            }
            unsigned ref = (unsigned)__shfl((int)v, 0);
            bool alleq = ok && (__ballot((v & 0xFFu) == (ref & 0xFFu)) == ~0ull);
            unsigned o = 0;
            int ok2 = 0;
            const unsigned* op = xccbuf + (c ^ 1);
            for (int it = 0; it < SPIN_BOUND; ++it) {
                o = ald4(op);
                if (o >= 0x100u) { ok2 = 1; break; }
                __builtin_amdgcn_s_sleep(2);
            }
            bool cand = alleq && ok2 && ((o & 0xFFu) != (ref & 0xFFu));
            if (lane == 0) verdLds = cand ? 1 : 0;
        }
    }
    __syncthreads();
    const bool candFast = (verdLds != 0);

    // ==== Phase 2: mechanism probe ====
    if (candFast && p == 0 && tid == 0) {
        for (unsigned k = 1; k <= 3; ++k) {
            st4_plain(probe + c * 32, k);
            asm volatile("s_waitcnt vmcnt(0)" ::: "memory");
            for (int s = 0; s < 32; ++s) __builtin_amdgcn_s_sleep(127);
        }
    }
    if (candFast && wid == 0) {
        unsigned first = 0xFFFFFFFFu;
        int got = 0;
        for (int it = 0; it < (1 << 16); ++it) {
            unsigned v = ld4_sc1(probe + c * 32);
            if (first == 0xFFFFFFFFu) first = v;
            if (v >= 3u) { got = 1; break; }
            __builtin_amdgcn_s_sleep(2);
        }
        if (p != 0 && first >= 3u) got = 0;
        if (lane == 0) mechLds = got;
    }
    __syncthreads();
    const int saw = candFast ? mechLds : 0;

    // ==== Phase 3: consensus ====
    if (tid == 0) ast4(mech + blockIdx.x, 0x100u | (unsigned)(saw & 1));
    if (wid == 0) {
        const unsigned* mp = mech + ((lane & 31) * 8 + c);
        unsigned v = 0;
        int ok = 0;
        for (int it = 0; it < SPIN_BOUND; ++it) {
            v = ald4(mp);
            if (__ballot(v >= 0x100u) == ~0ull) { ok = 1; break; }
            __builtin_amdgcn_s_sleep(2);
        }
        bool allsaw = ok && (__ballot((v & 1u) != 0u) == ~0ull);
        if (lane == 0) fastLds = (candFast && allsaw) ? 1 : 0;
    }

    const int colIdx = tid & 15;
    const int col    = p * HC_ + colIdx;
    const int row0   = tid >> 4;
    const int fkt  = col >> 5;
    const int fl4  = (col >> 3) & 3;
    const int fj   = col & 7;
    float bb[4], w0r[4][3];
    #pragma unroll
    for (int q = 0; q < 4; ++q) bb[q] = bgp[q * H_ + col];
    if (!isL2) {
        #pragma unroll
        for (int q = 0; q < 4; ++q)
            #pragma unroll
            for (int d = 0; d < 3; ++d)
                w0r[q][d] = W0[(size_t)(q * H_ + col) * 3 + d];
    }

    float cS[2] = {0.f, 0.f}, nS[2] = {0.f, 0.f}, mS[2] = {0.f, 0.f};
    const int kt0 = wid * 4;
    int dead = 0;

    __syncthreads();
    const bool fast = (fastLds != 0);

    // ============================ REAL LOOP ============================
    for (int t = 0; t < T_; ++t) {
        if (!isL2) {
            float xa[2][3];
            #pragma unroll
            for (int h = 0; h < 2; ++h) {
                const float* xp = xT + ((size_t)t * B_ + b0g + row0 + h * 16) * 3;
                xa[h][0] = xp[0]; xa[h][1] = xp[1]; xa[h][2] = xp[2];
            }
            #pragma unroll
            for (int q = 0; q < 4; ++q) {
                gbuf[gidx(q, row0, colIdx)] =
                    bb[q] + w0r[q][0]*xa[0][0] + w0r[q][1]*xa[0][1] + w0r[q][2]*xa[0][2];
                gbuf[gidx(q, row0 + 16, colIdx)] =
                    bb[q] + w0r[q][0]*xa[1][0] + w0r[q][1]*xa[1][1] + w0r[q][2]*xa[1][2];
            }
        } else {
            #pragma unroll
            for (int q = 0; q < 4; ++q) {
                gbuf[gidx(q, row0, colIdx)] = bb[q];
                gbuf[gidx(q, row0 + 16, colIdx)] = bb[q];
            }
        }

        f32x4 acc[2][4];
        #pragma unroll
        for (int mt = 0; mt < 2; ++mt)
            #pragma unroll
            for (int q = 0; q < 4; ++q) { f32x4 z = {0.f,0.f,0.f,0.f}; acc[mt][q] = z; }

        if (isL2) {
            if (!dead) {
                const unsigned* fx = flagX + ((size_t)(g * 32 + (lane & 31)) << 5);
                int it = 0;
                for (;;) {
                    unsigned v = ald4(fx);
                    if (__ballot(v >= (unsigned)(t + 1)) == ~0ull) break;
                    if (++it > SPIN_BOUND) { dead = 1; break; }
                    heat(v);
                }
            }
            asm volatile("" ::: "memory");
            f16x8 xh[4][2], xhB[4][2];
            const size_t tb = (((size_t)t * 4 + g) * 2) * FRAG_MT + kt0 * 512 + lane * 8;
            const _Float16* q0 = h1Fhi + tb;
            const _Float16* q1 = h1Fhi + tb + FRAG_MT;
            if (useH1Lo) {
                const _Float16* q2 = h1Flo + tb;
                const _Float16* q3 = h1Flo + tb + FRAG_MT;
                LD16C("sc0 sc1", xh, xhB, q0, q1, q2, q3);
            } else {
                asm volatile(
                    "global_load_dwordx4 %0, %8, off sc0 sc1\n\t"
                    "global_load_dwordx4 %1, %8, off offset:1024 sc0 sc1\n\t"
                    "global_load_dwordx4 %2, %8, off offset:2048 sc0 sc1\n\t"
                    "global_load_dwordx4 %3, %8, off offset:3072 sc0 sc1\n\t"
                    "global_load_dwordx4 %4, %9, off sc0 sc1\n\t"
                    "global_load_dwordx4 %5, %9, off offset:1024 sc0 sc1\n\t"
                    "global_load_dwordx4 %6, %9, off offset:2048 sc0 sc1\n\t"
                    "global_load_dwordx4 %7, %9, off offset:3072 sc0 sc1\n\t"
                    "s_waitcnt vmcnt(0)"
                    : "=&v"(xh[0][0]), "=&v"(xh[1][0]), "=&v"(xh[2][0]), "=&v"(xh[3][0]),
                      "=&v"(xh[0][1]), "=&v"(xh[1][1]), "=&v"(xh[2][1]), "=&v"(xh[3][1])
                    : "v"(q0), "v"(q1)
                    : "memory");
            }
            #pragma unroll
            for (int k = 0; k < 4; ++k)
                #pragma unroll
                for (int q = 0; q < 4; ++q) {
                    f16x8 w = *(const f16x8*)&lds[LDSH + ((q * 16 + kt0 + k) * 64 + lane) * 8];
                    acc[0][q] = MFMA(xh[k][0], w, acc[0][q]);
                    acc[1][q] = MFMA(xh[k][1], w, acc[1][q]);
                    if (useH1Lo) {
                        acc[0][q] = MFMA(xhB[k][0], w, acc[0][q]);
                        acc[1][q] = MFMA(xhB[k][1], w, acc[1][q]);
                    }
                }
        }

        if (t > 0 && !dead) {
            const unsigned* fr = flagR + ((size_t)(c * 32 + (lane & 31)) << 5);
            int it = 0;
            if (fast) {
                for (;;) {
                    unsigned v = ld4_sc1(fr);
                    if (__ballot(v >= (unsigned)t) == ~0ull) break;
                    if (++it > SPIN_BOUND) { dead = 1; break; }
                    heat(v);
                }
            } else {
                for (;;) {
                    unsigned v = ald4(fr);
                    if (__ballot(v >= (unsigned)t) == ~0ull) break;
                    if (++it > SPIN_BOUND) { dead = 1; break; }
                    heat(v);
                }
            }
            asm volatile("" ::: "memory");
        }

        f16x8 ah[4][2], ahB[4][2];
        {
            const size_t hb = (((size_t)(t & 1) * NC_ + c) * 2) * FRAG_MT + kt0 * 512 + lane * 8;
            const _Float16* ph0 = hexFhi + hb;
            const _Float16* ph1 = hexFhi + hb + FRAG_MT;
            const _Float16* pl0 = hexFlo + hb;
            const _Float16* pl1 = hexFlo + hb + FRAG_MT;
            if (fast) {
                LD16C("sc1", ah, ahB, ph0, ph1, pl0, pl1);
            } else {
                LD16C("sc0 sc1", ah, ahB, ph0, ph1, pl0, pl1);
            }
        }

        #pragma unroll
        for (int k = 0; k < 4; ++k)
            #pragma unroll
            for (int q = 0; q < 4; ++q) {
                f16x8 rh = *(const f16x8*)&lds[((q * 16 + kt0 + k) * 64 + lane) * 8];
                acc[0][q] = MFMA(ah[k][0], rh, acc[0][q]);
                acc[1][q] = MFMA(ah[k][1], rh, acc[1][q]);
                acc[0][q] = MFMA(ahB[k][0], rh, acc[0][q]);
                acc[1][q] = MFMA(ahB[k][1], rh, acc[1][q]);
                if (!isL2) {
                    f16x8 rlo = *(const f16x8*)&lds[LDSH + ((q * 16 + kt0 + k) * 64 + lane) * 8];
                    acc[0][q] = MFMA(ah[k][0], rlo, acc[0][q]);
                    acc[1][q] = MFMA(ah[k][1], rlo, acc[1][q]);
                }
            }

        __syncthreads();
        #pragma unroll
        for (int mt = 0; mt < 2; ++mt)
            #pragma unroll
            for (int q = 0; q < 4; ++q)
                #pragma unroll
                for (int r = 0; r < 4; ++r)
                    atomicAdd(&gbuf[gidx(q, mt * 16 + l4 * 4 + r, l15)], acc[mt][q][r]);
        __syncthreads();

        float hvv[2];
        unsigned pv[2][2];
        #pragma unroll
        for (int h = 0; h < 2; ++h) {
            const int row = row0 + h * 16;
            float iv = gbuf[gidx(0, row, colIdx)], fv = gbuf[gidx(1, row, colIdx)];
            float zv = gbuf[gidx(2, row, colIdx)], ov = gbuf[gidx(3, row, colIdx)];
            float fm = fv + mS[h];
            float mn = fmaxf(fm, iv);
            float ig = __expf(iv - mn);
            float fg = __expf(fm - mn);
            float zc = fminf(fmaxf(zv, -15.f), 15.f);
            float e2 = __expf(2.f * zc);
            float th = (e2 - 1.f) / (e2 + 1.f);
            cS[h] = fg * cS[h] + ig * th;
            nS[h] = fg * nS[h] + ig;
            mS[h] = mn;
            float sg = 1.f / (1.f + __expf(-ov));
            float hv = sg * cS[h] / fmaxf(nS[h], 1e-6f);
            hvv[h] = hv;

            _Float16 hi = (_Float16)hv;
            _Float16 lo = (_Float16)(hv - (float)hi);
            unsigned self = (unsigned)f16bits(hi) | ((unsigned)f16bits(lo) << 16);
            unsigned part = (unsigned)__shfl_xor((int)self, 1);
            pv[h][0] = (self & 0xffffu) | ((part & 0xffffu) << 16);
            pv[h][1] = (self >> 16) | (part & 0xffff0000u);
        }

        if (!(colIdx & 1)) {
            #pragma unroll
            for (int h = 0; h < 2; ++h) {
                const size_t fe = (((size_t)((t + 1) & 1) * NC_ + c) * 2 + h) * FRAG_MT
                                + fkt * 512 + (size_t)(row0 + 16 * fl4) * 8 + fj;
                if (fast) {
                    *(unsigned*)(hexFhi + fe) = pv[h][0];
                    *(unsigned*)(hexFlo + fe) = pv[h][1];
                } else {
                    ast4(hexFhi + fe, pv[h][0]);
                    ast4(hexFlo + fe, pv[h][1]);
                }
            }
        }
        asm volatile("s_waitcnt vmcnt(0)" ::: "memory");
        __syncthreads();
        if (tid == 0) {
            unsigned nv = (unsigned)(t + 1);
            unsigned* frp = flagR + ((size_t)(c * 32 + p) << 5);
            if (fast) st4_plain(frp, nv);
            else      ast4(frp, nv);
            if (!isL2) ast4(flagX + ((size_t)(c * 32 + p) << 5), (unsigned)t);
        }

        if (!isL2 && !(colIdx & 1)) {
            #pragma unroll
            for (int h = 0; h < 2; ++h) {
                const size_t fe = (((size_t)t * 4 + g) * 2 + h) * FRAG_MT
                                + fkt * 512 + (size_t)(row0 + 16 * fl4) * 8 + fj;
                ast4(h1Fhi + fe, pv[h][0]);
                if (useH1Lo) ast4(h1Flo + fe, pv[h][1]);
            }
        }

        if (isL2 && t == T_ - 1) {
            #pragma unroll
            for (int h = 0; h < 2; ++h)
                hlast[(size_t)(b0g + row0 + h * 16) * H_ + col] = hvv[h];
        }
    }

    if (!isL2) {
        asm volatile("s_waitcnt vmcnt(0)" ::: "memory");
        __syncthreads();
        if (tid == 0) ast4(flagX + ((size_t)(c * 32 + p) << 5), (unsigned)(T_ + 1));
    }

    // ===================== MIMIC PHASE (bisection #2) =====================
    // Full-step replica: identical structure, data indices frozen at t=0,
    // flag sequences continue past T. No hlast writes -> outputs untouched.
    for (int r = 0; r < MIMIC_R; ++r) {
        if (!isL2) {
            float xa[2][3];
            #pragma unroll
            for (int h = 0; h < 2; ++h) {
                const float* xp = xT + ((size_t)(b0g + row0 + h * 16)) * 3;   // t=0
                xa[h][0] = xp[0]; xa[h][1] = xp[1]; xa[h][2] = xp[2];
            }
            #pragma unroll
            for (int q = 0; q < 4; ++q) {
                gbuf[gidx(q, row0, colIdx)] =
                    bb[q] + w0r[q][0]*xa[0][0] + w0r[q][1]*xa[0][1] + w0r[q][2]*xa[0][2];
                gbuf[gidx(q, row0 + 16, colIdx)] =
                    bb[q] + w0r[q][0]*xa[1][0] + w0r[q][1]*xa[1][1] + w0r[q][2]*xa[1][2];
            }
        } else {
            #pragma unroll
            for (int q = 0; q < 4; ++q) {
                gbuf[gidx(q, row0, colIdx)] = bb[q];
                gbuf[gidx(q, row0 + 16, colIdx)] = bb[q];
            }
        }

        f32x4 acc[2][4];
        #pragma unroll
        for (int mt = 0; mt < 2; ++mt)
            #pragma unroll
            for (int q = 0; q < 4; ++q) { f32x4 z = {0.f,0.f,0.f,0.f}; acc[mt][q] = z; }

        if (isL2) {
            if (!dead) {
                const unsigned* fx = flagX + ((size_t)(g * 32 + (lane & 31)) << 5);
                int it = 0;
                for (;;) {
                    unsigned v = ald4(fx);
                    if (__ballot(v >= (unsigned)(T_ + 1 + r)) == ~0ull) break;
                    if (++it > SPIN_BOUND) { dead = 1; break; }
                    heat(v);
                }
            }
            asm volatile("" ::: "memory");
            f16x8 xh[4][2], xhB[4][2];
            const size_t tb = ((size_t)g * 2) * FRAG_MT + kt0 * 512 + lane * 8;  // t=0
            const _Float16* q0 = h1Fhi + tb;
            const _Float16* q1 = h1Fhi + tb + FRAG_MT;
            if (useH1Lo) {
                const _Float16* q2 = h1Flo + tb;
                const _Float16* q3 = h1Flo + tb + FRAG_MT;
                LD16C("sc0 sc1", xh, xhB, q0, q1, q2, q3);
            } else {
                asm volatile(
                    "global_load_dwordx4 %0, %8, off sc0 sc1\n\t"
                    "global_load_dwordx4 %1, %8, off offset:1024 sc0 sc1\n\t"
                    "global_load_dwordx4 %2, %8, off offset:2048 sc0 sc1\n\t"
                    "global_load_dwordx4 %3, %8, off offset:3072 sc0 sc1\n\t"
                    "global_load_dwordx4 %4, %9, off sc0 sc1\n\t"
                    "global_load_dwordx4 %5, %9, off offset:1024 sc0 sc1\n\t"
                    "global_load_dwordx4 %6, %9, off offset:2048 sc0 sc1\n\t"
                    "global_load_dwordx4 %7, %9, off offset:3072 sc0 sc1\n\t"
                    "s_waitcnt vmcnt(0)"
                    : "=&v"(xh[0][0]), "=&v"(xh[1][0]), "=&v"(xh[2][0]), "=&v"(xh[3][0]),
                      "=&v"(xh[0][1]), "=&v"(xh[1][1]), "=&v"(xh[2][1]), "=&v"(xh[3][1])
                    : "v"(q0), "v"(q1)
                    : "memory");
            }
            #pragma unroll
            for (int k = 0; k < 4; ++k)
                #pragma unroll
                for (int q = 0; q < 4; ++q) {
                    f16x8 w = *(const f16x8*)&lds[LDSH + ((q * 16 + kt0 + k) * 64 + lane) * 8];
                    acc[0][q] = MFMA(xh[k][0], w, acc[0][q]);
                    acc[1][q] = MFMA(xh[k][1], w, acc[1][q]);
                    if (useH1Lo) {
                        acc[0][q] = MFMA(xhB[k][0], w, acc[0][q]);
                        acc[1][q] = MFMA(xhB[k][1], w, acc[1][q]);
                    }
                }
        }

        if (!dead) {   // poll previous round's flagR (r=0: target T_, already set)
            const unsigned* fr = flagR + ((size_t)(c * 32 + (lane & 31)) << 5);
            int it = 0;
            if (fast) {
                for (;;) {
                    unsigned v = ld4_sc1(fr);
                    if (__ballot(v >= (unsigned)(T_ + r)) == ~0ull) break;
                    if (++it > SPIN_BOUND) { dead = 1; break; }
                    heat(v);
                }
            } else {
                for (;;) {
                    unsigned v = ald4(fr);
                    if (__ballot(v >= (unsigned)(T_ + r)) == ~0ull) break;
                    if (++it > SPIN_BOUND) { dead = 1; break; }
                    heat(v);
                }
            }
            asm volatile("" ::: "memory");
        }

        f16x8 ah[4][2], ahB[4][2];
        {
            const size_t hb = (((size_t)((T_ + r) & 1) * NC_ + c) * 2) * FRAG_MT
                            + kt0 * 512 + lane * 8;
            const _Float16* ph0 = hexFhi + hb;
            const _Float16* ph1 = hexFhi + hb + FRAG_MT;
            const _Float16* pl0 = hexFlo + hb;
            const _Float16* pl1 = hexFlo + hb + FRAG_MT;
            if (fast) {
                LD16C("sc1", ah, ahB, ph0, ph1, pl0, pl1);
            } else {
                LD16C("sc0 sc1", ah, ahB, ph0, ph1, pl0, pl1);
            }
        }

        #pragma unroll
        for (int k = 0; k < 4; ++k)
            #pragma unroll
            for (int q = 0; q < 4; ++q) {
                f16x8 rh = *(const f16x8*)&lds[((q * 16 + kt0 + k) * 64 + lane) * 8];
                acc[0][q] = MFMA(ah[k][0], rh, acc[0][q]);
                acc[1][q] = MFMA(ah[k][1], rh, acc[1][q]);
                acc[0][q] = MFMA(ahB[k][0], rh, acc[0][q]);
                acc[1][q] = MFMA(ahB[k][1], rh, acc[1][q]);
                if (!isL2) {
                    f16x8 rlo = *(const f16x8*)&lds[LDSH + ((q * 16 + kt0 + k) * 64 + lane) * 8];
                    acc[0][q] = MFMA(ah[k][0], rlo, acc[0][q]);
                    acc[1][q] = MFMA(ah[k][1], rlo, acc[1][q]);
                }
            }

        __syncthreads();
        #pragma unroll
        for (int mt = 0; mt < 2; ++mt)
            #pragma unroll
            for (int q = 0; q < 4; ++q)
                #pragma unroll
                for (int rr = 0; rr < 4; ++rr)
                    atomicAdd(&gbuf[gidx(q, mt * 16 + l4 * 4 + rr, l15)], acc[mt][q][rr]);
        __syncthreads();

        unsigned pv[2][2];
        #pragma unroll
        for (int h = 0; h < 2; ++h) {
            const int row = row0 + h * 16;
            float iv = gbuf[gidx(0, row, colIdx)], fv = gbuf[gidx(1, row, colIdx)];
            float zv = gbuf[gidx(2, row, colIdx)], ov = gbuf[gidx(3, row, colIdx)];
            float fm = fv + mS[h];
            float mn = fmaxf(fm, iv);
            float ig = __expf(iv - mn);
            float fg = __expf(fm - mn);
            float zc = fminf(fmaxf(zv, -15.f), 15.f);
            float e2 = __expf(2.f * zc);
            float th = (e2 - 1.f) / (e2 + 1.f);
            cS[h] = fg * cS[h] + ig * th;
            nS[h] = fg * nS[h] + ig;
            mS[h] = mn;
            float sg = 1.f / (1.f + __expf(-ov));
            float hv = sg * cS[h] / fmaxf(nS[h], 1e-6f);

            _Float16 hi = (_Float16)hv;
            _Float16 lo = (_Float16)(hv - (float)hi);
            unsigned self = (unsigned)f16bits(hi) | ((unsigned)f16bits(lo) << 16);
            unsigned part = (unsigned)__shfl_xor((int)self, 1);
            pv[h][0] = (self & 0xffffu) | ((part & 0xffffu) << 16);
            pv[h][1] = (self >> 16) | (part & 0xffff0000u);
        }

        if (!(colIdx & 1)) {
            #pragma unroll
            for (int h = 0; h < 2; ++h) {
                const size_t fe = (((size_t)((T_ + 1 + r) & 1) * NC_ + c) * 2 + h) * FRAG_MT
                                + fkt * 512 + (size_t)(row0 + 16 * fl4) * 8 + fj;
                if (fast) {
                    *(unsigned*)(hexFhi + fe) = pv[h][0];
                    *(unsigned*)(hexFlo + fe) = pv[h][1];
                } else {
                    ast4(hexFhi + fe, pv[h][0]);
                    ast4(hexFlo + fe, pv[h][1]);
                }
            }
        }
        asm volatile("s_waitcnt vmcnt(0)" ::: "memory");
        __syncthreads();
        if (tid == 0) {
            unsigned nv = (unsigned)(T_ + 1 + r);
            unsigned* frp = flagR + ((size_t)(c * 32 + p) << 5);
            if (fast) st4_plain(frp, nv);
            else      ast4(frp, nv);
            if (!isL2) ast4(flagX + ((size_t)(c * 32 + p) << 5), nv);
        }

        if (!isL2 && !(colIdx & 1)) {    // h1F[0] stores (consumed already; junk ok)
            #pragma unroll
            for (int h = 0; h < 2; ++h) {
                const size_t fe = (((size_t)g * 2 + h) * FRAG_MT)
                                + fkt * 512 + (size_t)(row0 + 16 * fl4) * 8 + fj;
                ast4(h1Fhi + fe, pv[h][0]);
                if (useH1Lo) ast4(h1Flo + fe, pv[h][1]);
            }
        }
    }
}

#define OUT_ 26
__global__ __launch_bounds__(64)
void fc_kernel(const float* __restrict__ hlast, const float* __restrict__ fcw,
               const float* __restrict__ fcb, float* __restrict__ out)
{
    int b = blockIdx.x, o = threadIdx.x;
    if (o < OUT_) {
        const float4* hv = reinterpret_cast<const float4*>(hlast + (size_t)b * H_);
        const float4* wv = reinterpret_cast<const float4*>(fcw + (size_t)o * H_);
        float s = fcb[o];
        #pragma unroll 4
        for (int k = 0; k < H_ / 4; ++k) {
            float4 h4 = hv[k], w4 = wv[k];
            s += h4.x * w4.x + h4.y * w4.y + h4.z * w4.z + h4.w * w4.w;
        }
        out[(size_t)b * OUT_ + o] = s;
    }
}

extern "C" void kernel_launch(void* const* d_in, const int* in_sizes, int n_in,
                              void* d_out, int out_size, void* d_ws, size_t ws_size,
                              hipStream_t stream) {
    const float* x   = (const float*)d_in[0];
    const float* W0  = (const float*)d_in[1];
    const float* R0  = (const float*)d_in[2];
    const float* b0  = (const float*)d_in[3];
    const float* W1  = (const float*)d_in[4];
    const float* R1  = (const float*)d_in[5];
    const float* b1  = (const float*)d_in[6];
    const float* fcw = (const float*)d_in[7];
    const float* fcb = (const float*)d_in[8];
    float* out = (float*)d_out;

    if (ws_size < WS_NEED_SMALL) return;
    const int useH1Lo = (ws_size >= WS_NEED_FULL) ? 1 : 0;

    char* ws = (char*)d_ws;
    _Float16* hexFhi = (_Float16*)(ws + WS_HEXHI);
    _Float16* hexFlo = (_Float16*)(ws + WS_HEXLO);
    unsigned* flagR  = (unsigned*)(ws + WS_FLAGR);
    unsigned* flagX  = (unsigned*)(ws + WS_FLAGX);
    unsigned* xccb   = (unsigned*)(ws + WS_XCC);
    unsigned* mech   = (unsigned*)(ws + WS_MECH);
    unsigned* probe  = (unsigned*)(ws + WS_PROBE);
    float*    xTp    = (float*)(ws + WS_XT);
    float*    hlast  = (float*)(ws + WS_HLAST);
    _Float16* h1Fhi  = (_Float16*)(ws + WS_H1HI);
    _Float16* h1Flo  = (_Float16*)(ws + WS_H1LO);

    hipMemsetAsync(ws, 0, WS_ZEROL, stream);
    xt_kernel<<<(B_ * T_ * 3 + 255) / 256, 256, 0, stream>>>(x, xTp);
    fused_slstm<<<NC_ * P_, NW_ * 64, 0, stream>>>(xTp, W0, R0, b0, W1, R1, b1,
                                                   hexFhi, hexFlo, flagR, flagX,
                                                   xccb, mech, probe,
                                                   h1Fhi, h1Flo, hlast, useH1Lo);
    fc_kernel<<<B_, 64, 0, stream>>>(hlast, fcw, fcb, out);
}

// Round 17
// 5562.057 us; speedup vs baseline: 5.2603x; 5.2603x over previous
//
#include <hip/hip_runtime.h>
#include <hip/hip_bf16.h>

typedef _Float16 f16x8 __attribute__((ext_vector_type(8)));
typedef float f32x4 __attribute__((ext_vector_type(4)));
typedef unsigned long long u64;

#define B_   128
#define T_   1024
#define H_   512
#define P_   32
#define HC_  16
#define MB_  32
#define NC_  8
#define NW_  4
#define SPIN_BOUND (1 << 20)

#define FRAG_MT 8192

// ws layout (bytes)
#define WS_HEXHI  0ull
#define WS_HEXLO  524288ull
#define WS_FLAGR  1048576ull      // u32 [NC][32] PACKED: one 128B line per clique
#define WS_FLAGX  1081344ull      // u32 [4][32] packed
#define WS_XCC    1097728ull
#define WS_MECH   1098752ull
#define WS_PROBE  1099776ull
#define WS_ZEROL  1100800ull
#define WS_XT     1100800ull
#define WS_HLAST  2673664ull
#define WS_H1HI   2935808ull
#define WS_H1LO   137153536ull
#define WS_NEED_SMALL 137153536ull
#define WS_NEED_FULL  271371264ull

#define MFMA(a, b, c) __builtin_amdgcn_mfma_f32_16x16x32_f16((a), (b), (c), 0, 0, 0)

// 16 coalesced dwordx4 loads, ONE vmcnt(0) (r15 structure, unchanged).
#define LD16C(FLAGS, D, DB, P0, P1, P2, P3)                                     \
    asm volatile(                                                               \
        "global_load_dwordx4 %0, %16, off " FLAGS "\n\t"                        \
        "global_load_dwordx4 %1, %16, off offset:1024 " FLAGS "\n\t"            \
        "global_load_dwordx4 %2, %16, off offset:2048 " FLAGS "\n\t"            \
        "global_load_dwordx4 %3, %16, off offset:3072 " FLAGS "\n\t"            \
        "global_load_dwordx4 %4, %17, off " FLAGS "\n\t"                        \
        "global_load_dwordx4 %5, %17, off offset:1024 " FLAGS "\n\t"            \
        "global_load_dwordx4 %6, %17, off offset:2048 " FLAGS "\n\t"            \
        "global_load_dwordx4 %7, %17, off offset:3072 " FLAGS "\n\t"            \
        "global_load_dwordx4 %8, %18, off " FLAGS "\n\t"                        \
        "global_load_dwordx4 %9, %18, off offset:1024 " FLAGS "\n\t"            \
        "global_load_dwordx4 %10, %18, off offset:2048 " FLAGS "\n\t"           \
        "global_load_dwordx4 %11, %18, off offset:3072 " FLAGS "\n\t"           \
        "global_load_dwordx4 %12, %19, off " FLAGS "\n\t"                       \
        "global_load_dwordx4 %13, %19, off offset:1024 " FLAGS "\n\t"           \
        "global_load_dwordx4 %14, %19, off offset:2048 " FLAGS "\n\t"           \
        "global_load_dwordx4 %15, %19, off offset:3072 " FLAGS "\n\t"           \
        "s_waitcnt vmcnt(0)"                                                    \
        : "=&v"(D[0][0]), "=&v"(D[1][0]), "=&v"(D[2][0]), "=&v"(D[3][0]),       \
          "=&v"(D[0][1]), "=&v"(D[1][1]), "=&v"(D[2][1]), "=&v"(D[3][1]),       \
          "=&v"(DB[0][0]), "=&v"(DB[1][0]), "=&v"(DB[2][0]), "=&v"(DB[3][0]),   \
          "=&v"(DB[0][1]), "=&v"(DB[1][1]), "=&v"(DB[2][1]), "=&v"(DB[3][1])    \
        : "v"(P0), "v"(P1), "v"(P2), "v"(P3)                                    \
        : "memory")

__device__ __forceinline__ unsigned ald4(const unsigned* p) {
    return __hip_atomic_load(p, __ATOMIC_RELAXED, __HIP_MEMORY_SCOPE_AGENT);
}
__device__ __forceinline__ void ast4(void* p, unsigned v) {
    __hip_atomic_store((unsigned*)p, v, __ATOMIC_RELAXED, __HIP_MEMORY_SCOPE_AGENT);
}
__device__ __forceinline__ void st4_plain(unsigned* p, unsigned v) {
    asm volatile("global_store_dword %0, %1, off" :: "v"(p), "v"(v) : "memory");
}
__device__ __forceinline__ unsigned ld4_sc1(const unsigned* p) {
    unsigned r;
    asm volatile("global_load_dword %0, %1, off sc1\n\ts_waitcnt vmcnt(0)"
                 : "=v"(r) : "v"(p) : "memory");
    return r;
}
__device__ __forceinline__ void st16_plain(void* p, f16x8 v) {
    asm volatile("global_store_dwordx4 %0, %1, off" :: "v"(p), "v"(v) : "memory");
}
__device__ __forceinline__ void st16_ic(void* p, f16x8 v) {
    asm volatile("global_store_dwordx4 %0, %1, off sc0 sc1" :: "v"(p), "v"(v) : "memory");
}
__device__ __forceinline__ unsigned short f16bits(_Float16 h) {
    union { _Float16 f; unsigned short s; } u; u.f = h; return u.s;
}
__device__ __forceinline__ void heat(unsigned v) {
    float a = (float)(v & 7u) + 1.0f;
    #pragma unroll
    for (int i = 0; i < 16; ++i)
        asm volatile("v_fmac_f32 %0, %1, %2" : "+v"(a) : "v"(1.000001f), "v"(a));
    asm volatile("" :: "v"(a));
}

__global__ __launch_bounds__(256)
void xt_kernel(const float* __restrict__ x, float* __restrict__ xT) {
    int idx = blockIdx.x * 256 + threadIdx.x;
    if (idx < B_ * T_ * 3) {
        int d = idx % 3, rest = idx / 3;
        int t = rest % T_, b = rest / T_;
        xT[((size_t)t * B_ + b) * 3 + d] = x[idx];
    }
}

// 256 blocks x 256 threads. LDS: 128KB weights + 8KB partial buffer.
// Reduce: plain-LDS chained passes w1(init+bias+x) -> w2 += -> w3 += -> w0 +=.
// Wave 0 alone does state math + DENSE dwordx4 stores + flag publish.
__global__ __launch_bounds__(256, 1)
void fused_slstm(const float* __restrict__ xT,
                 const float* __restrict__ W0, const float* __restrict__ R0,
                 const float* __restrict__ b0v,
                 const float* __restrict__ W1, const float* __restrict__ R1,
                 const float* __restrict__ b1v,
                 _Float16* __restrict__ hexFhi, _Float16* __restrict__ hexFlo,
                 unsigned* __restrict__ flagR, unsigned* __restrict__ flagX,
                 unsigned* __restrict__ xccbuf, unsigned* __restrict__ mech,
                 unsigned* __restrict__ probe,
                 _Float16* __restrict__ h1Fhi, _Float16* __restrict__ h1Flo,
                 float* __restrict__ hlast, int useH1Lo)
{
    constexpr int LDSH = 4 * 16 * 64 * 8;
    __shared__ _Float16 lds[2 * LDSH];
    __shared__ float pbuf[2048];          // [mt][q][lane][r] natural-layout partials
    __shared__ int verdLds, mechLds, fastLds;

    const int tid  = threadIdx.x;
    const int lane = tid & 63;
    const int wid  = tid >> 6;
    const int l15  = lane & 15;
    const int l4   = lane >> 4;
    const int kg8  = l4 * 8;
    const int c    = blockIdx.x & 7;
    const int p    = blockIdx.x >> 3;
    const bool isL2 = (c >= 4);
    const int g    = c & 3;
    const int b0g  = g * MB_;

    const float* Rg  = isL2 ? R1 : R0;
    const float* bgp = isL2 ? b1v : b0v;

    // ---- stage weights (frag-major f16), wave wid -> gate q=wid ----
    {
        const int q = wid;
        const int grow = q * H_ + p * HC_ + l15;
        const float* rsrc = Rg + (size_t)grow * H_ + kg8;
        for (int kt = 0; kt < 16; ++kt) {
            const float* s = rsrc + kt * 32;
            _Float16* dhi = &lds[((q * 16 + kt) * 64 + lane) * 8];
            _Float16* dlo = dhi + LDSH;
            if (!isL2) {
                #pragma unroll
                for (int j = 0; j < 8; ++j) {
                    float v = s[j];
                    _Float16 h = (_Float16)v;
                    dhi[j] = h;
                    dlo[j] = (_Float16)(v - (float)h);
                }
            } else {
                const float* ws2 = W1 + (size_t)grow * H_ + kt * 32 + kg8;
                #pragma unroll
                for (int j = 0; j < 8; ++j) {
                    dhi[j] = (_Float16)s[j];
                    dlo[j] = (_Float16)ws2[j];
                }
            }
        }
    }

    // ==== Phase 1: XCC mapping verdict ====
    {
        unsigned myxcc;
        asm volatile("s_getreg_b32 %0, hwreg(20, 0, 32)" : "=s"(myxcc));
        if (tid == 0) ast4(xccbuf + blockIdx.x, 0x100u | (myxcc & 0xFFu));
        if (wid == 0) {
            const unsigned* xp = xccbuf + ((lane & 31) * 8 + c);
            unsigned v = 0;
            int ok = 0;
            for (int it = 0; it < SPIN_BOUND; ++it) {
                v = ald4(xp);
                if (__ballot(v >= 0x100u) == ~0ull) { ok = 1; break; }
                __builtin_amdgcn_s_sleep(2);
            }
            unsigned ref = (unsigned)__shfl((int)v, 0);
            bool alleq = ok && (__ballot((v & 0xFFu) == (ref & 0xFFu)) == ~0ull);
            unsigned o = 0;
            int ok2 = 0;
            const unsigned* op = xccbuf + (c ^ 1);
            for (int it = 0; it < SPIN_BOUND; ++it) {
                o = ald4(op);
                if (o >= 0x100u) { ok2 = 1; break; }
                __builtin_amdgcn_s_sleep(2);
            }
            bool cand = alleq && ok2 && ((o & 0xFFu) != (ref & 0xFFu));
            if (lane == 0) verdLds = cand ? 1 : 0;
        }
    }
    __syncthreads();
    const bool candFast = (verdLds != 0);

    // ==== Phase 2: mechanism probe ====
    if (candFast && p == 0 && tid == 0) {
        for (unsigned k = 1; k <= 3; ++k) {
            st4_plain(probe + c * 32, k);
            asm volatile("s_waitcnt vmcnt(0)" ::: "memory");
            for (int s = 0; s < 32; ++s) __builtin_amdgcn_s_sleep(127);
        }
    }
    if (candFast && wid == 0) {
        unsigned first = 0xFFFFFFFFu;
        int got = 0;
        for (int it = 0; it < (1 << 16); ++it) {
            unsigned v = ld4_sc1(probe + c * 32);
            if (first == 0xFFFFFFFFu) first = v;
            if (v >= 3u) { got = 1; break; }
            __builtin_amdgcn_s_sleep(2);
        }
        if (p != 0 && first >= 3u) got = 0;
        if (lane == 0) mechLds = got;
    }
    __syncthreads();
    const int saw = candFast ? mechLds : 0;

    // ==== Phase 3: consensus ====
    if (tid == 0) ast4(mech + blockIdx.x, 0x100u | (unsigned)(saw & 1));
    if (wid == 0) {
        const unsigned* mp = mech + ((lane & 31) * 8 + c);
        unsigned v = 0;
        int ok = 0;
        for (int it = 0; it < SPIN_BOUND; ++it) {
            v = ald4(mp);
            if (__ballot(v >= 0x100u) == ~0ull) { ok = 1; break; }
            __builtin_amdgcn_s_sleep(2);
        }
        bool allsaw = ok && (__ballot((v & 1u) != 0u) == ~0ull);
        if (lane == 0) fastLds = (candFast && allsaw) ? 1 : 0;
    }

    // ---- wave-1 constants (bias + input-projection weights, per-lane col=l15) ----
    float bb[4], w0r[4][3];
    if (wid == 1 || wid == 0) {     // wave0 unused but harmless; wave1 needs them
        const int col = p * HC_ + l15;
        #pragma unroll
        for (int q = 0; q < 4; ++q) bb[q] = bgp[q * H_ + col];
        if (!isL2) {
            #pragma unroll
            for (int q = 0; q < 4; ++q)
                #pragma unroll
                for (int d = 0; d < 3; ++d)
                    w0r[q][d] = W0[(size_t)(q * H_ + col) * 3 + d];
        }
    }

    // ---- wave-0 state-lane geometry: 8 elements = (mt0, row r15, cols o*8..o*8+7) ----
    const int o    = (lane >> 4) & 1;
    const int mt0  = lane >> 5;
    const int r15  = lane & 15;
    const int fl4s = (p & 1) * 2 + o;
    const int fkt  = p >> 1;
    float cS[8], nS[8], mS[8];
    #pragma unroll
    for (int j = 0; j < 8; ++j) { cS[j] = 0.f; nS[j] = 0.f; mS[j] = 0.f; }

    const int kt0 = wid * 4;
    int dead = 0;

    __syncthreads();
    const bool fast = (fastLds != 0);

    for (int t = 0; t < T_; ++t) {
        f32x4 acc[2][4];
        #pragma unroll
        for (int mt = 0; mt < 2; ++mt)
            #pragma unroll
            for (int q = 0; q < 4; ++q) { f32x4 z = {0.f,0.f,0.f,0.f}; acc[mt][q] = z; }

        // ---- L2 feed-forward: poll flagX (packed line), h1F loads + W1 MFMAs ----
        if (isL2) {
            if (!dead) {
                const unsigned* fx = flagX + g * 32 + (lane & 31);
                int it = 0;
                for (;;) {
                    unsigned v = fast ? ld4_sc1(fx) : ald4(fx);
                    if (__ballot(v >= (unsigned)(t + 1)) == ~0ull) break;
                    if (++it > SPIN_BOUND) { dead = 1; break; }
                    heat(v);
                }
            }
            asm volatile("" ::: "memory");
            f16x8 xh[4][2], xhB[4][2];
            const size_t tb = (((size_t)t * 4 + g) * 2) * FRAG_MT + kt0 * 512 + lane * 8;
            const _Float16* q0 = h1Fhi + tb;
            const _Float16* q1 = h1Fhi + tb + FRAG_MT;
            if (useH1Lo) {
                const _Float16* q2 = h1Flo + tb;
                const _Float16* q3 = h1Flo + tb + FRAG_MT;
                LD16C("sc0 sc1", xh, xhB, q0, q1, q2, q3);
            } else {
                asm volatile(
                    "global_load_dwordx4 %0, %8, off sc0 sc1\n\t"
                    "global_load_dwordx4 %1, %8, off offset:1024 sc0 sc1\n\t"
                    "global_load_dwordx4 %2, %8, off offset:2048 sc0 sc1\n\t"
                    "global_load_dwordx4 %3, %8, off offset:3072 sc0 sc1\n\t"
                    "global_load_dwordx4 %4, %9, off sc0 sc1\n\t"
                    "global_load_dwordx4 %5, %9, off offset:1024 sc0 sc1\n\t"
                    "global_load_dwordx4 %6, %9, off offset:2048 sc0 sc1\n\t"
                    "global_load_dwordx4 %7, %9, off offset:3072 sc0 sc1\n\t"
                    "s_waitcnt vmcnt(0)"
                    : "=&v"(xh[0][0]), "=&v"(xh[1][0]), "=&v"(xh[2][0]), "=&v"(xh[3][0]),
                      "=&v"(xh[0][1]), "=&v"(xh[1][1]), "=&v"(xh[2][1]), "=&v"(xh[3][1])
                    : "v"(q0), "v"(q1)
                    : "memory");
            }
            #pragma unroll
            for (int k = 0; k < 4; ++k)
                #pragma unroll
                for (int q = 0; q < 4; ++q) {
                    f16x8 w = *(const f16x8*)&lds[LDSH + ((q * 16 + kt0 + k) * 64 + lane) * 8];
                    acc[0][q] = MFMA(xh[k][0], w, acc[0][q]);
                    acc[1][q] = MFMA(xh[k][1], w, acc[1][q]);
                    if (useH1Lo) {
                        acc[0][q] = MFMA(xhB[k][0], w, acc[0][q]);
                        acc[1][q] = MFMA(xhB[k][1], w, acc[1][q]);
                    }
                }
        }

        // ---- recurrent wait: packed-line poll ----
        if (t > 0 && !dead) {
            const unsigned* fr = flagR + c * 32 + (lane & 31);
            int it = 0;
            for (;;) {
                unsigned v = fast ? ld4_sc1(fr) : ald4(fr);
                if (__ballot(v >= (unsigned)t) == ~0ull) break;
                if (++it > SPIN_BOUND) { dead = 1; break; }
                heat(v);
            }
            asm volatile("" ::: "memory");
        }

        // ---- recurrent A-frags (coalesced) + MFMAs ----
        f16x8 ah[4][2], ahB[4][2];
        {
            const size_t hb = (((size_t)(t & 1) * NC_ + c) * 2) * FRAG_MT + kt0 * 512 + lane * 8;
            const _Float16* ph0 = hexFhi + hb;
            const _Float16* ph1 = hexFhi + hb + FRAG_MT;
            const _Float16* pl0 = hexFlo + hb;
            const _Float16* pl1 = hexFlo + hb + FRAG_MT;
            if (fast) { LD16C("sc1", ah, ahB, ph0, ph1, pl0, pl1); }
            else      { LD16C("sc0 sc1", ah, ahB, ph0, ph1, pl0, pl1); }
        }
        #pragma unroll
        for (int k = 0; k < 4; ++k)
            #pragma unroll
            for (int q = 0; q < 4; ++q) {
                f16x8 rh = *(const f16x8*)&lds[((q * 16 + kt0 + k) * 64 + lane) * 8];
                acc[0][q] = MFMA(ah[k][0], rh, acc[0][q]);
                acc[1][q] = MFMA(ah[k][1], rh, acc[1][q]);
                acc[0][q] = MFMA(ahB[k][0], rh, acc[0][q]);
                acc[1][q] = MFMA(ahB[k][1], rh, acc[1][q]);
                if (!isL2) {
                    f16x8 rlo = *(const f16x8*)&lds[LDSH + ((q * 16 + kt0 + k) * 64 + lane) * 8];
                    acc[0][q] = MFMA(ah[k][0], rlo, acc[0][q]);
                    acc[1][q] = MFMA(ah[k][1], rlo, acc[1][q]);
                }
            }

        // ---- atomic-free reduce: w1 init(+bias+x) -> w2 += -> w3 += -> w0 += ----
        f32x4* pb = (f32x4*)pbuf;
        if (wid == 1) {
            float xa[2][4][3];
            if (!isL2) {
                #pragma unroll
                for (int mt = 0; mt < 2; ++mt)
                    #pragma unroll
                    for (int r = 0; r < 4; ++r) {
                        const float* xp = xT + ((size_t)t * B_ + b0g + mt * 16 + l4 * 4 + r) * 3;
                        xa[mt][r][0] = xp[0]; xa[mt][r][1] = xp[1]; xa[mt][r][2] = xp[2];
                    }
            }
            #pragma unroll
            for (int mt = 0; mt < 2; ++mt)
                #pragma unroll
                for (int q = 0; q < 4; ++q) {
                    f32x4 v = acc[mt][q];
                    #pragma unroll
                    for (int r = 0; r < 4; ++r) {
                        float e = bb[q];
                        if (!isL2)
                            e += w0r[q][0]*xa[mt][r][0] + w0r[q][1]*xa[mt][r][1]
                               + w0r[q][2]*xa[mt][r][2];
                        v[r] += e;
                    }
                    pb[(mt * 4 + q) * 64 + lane] = v;
                }
        }
        __syncthreads();                       // bar1
        if (wid == 2) {
            #pragma unroll
            for (int mt = 0; mt < 2; ++mt)
                #pragma unroll
                for (int q = 0; q < 4; ++q) {
                    f32x4 v = pb[(mt * 4 + q) * 64 + lane];
                    v += acc[mt][q];
                    pb[(mt * 4 + q) * 64 + lane] = v;
                }
        }
        __syncthreads();                       // bar2
        if (wid == 3) {
            #pragma unroll
            for (int mt = 0; mt < 2; ++mt)
                #pragma unroll
                for (int q = 0; q < 4; ++q) {
                    f32x4 v = pb[(mt * 4 + q) * 64 + lane];
                    v += acc[mt][q];
                    pb[(mt * 4 + q) * 64 + lane] = v;
                }
        }
        __syncthreads();                       // bar3

        // ---- wave 0: final +=, transposed gate reads, state math, DENSE stores ----
        if (wid == 0) {
            #pragma unroll
            for (int mt = 0; mt < 2; ++mt)
                #pragma unroll
                for (int q = 0; q < 4; ++q) {
                    f32x4 v = pb[(mt * 4 + q) * 64 + lane];
                    v += acc[mt][q];
                    pb[(mt * 4 + q) * 64 + lane] = v;
                }

            float gq[4][8];
            #pragma unroll
            for (int q = 0; q < 4; ++q)
                #pragma unroll
                for (int j = 0; j < 8; ++j) {
                    const int lane2 = ((r15 >> 2) << 4) + o * 8 + j;
                    gq[q][j] = pbuf[((mt0 * 4 + q) * 64 + lane2) * 4 + (r15 & 3)];
                }

            union { _Float16 h[8]; f16x8 v; } uh, ul;
            float hv8[8];
            #pragma unroll
            for (int j = 0; j < 8; ++j) {
                float iv = gq[0][j], fv = gq[1][j], zv = gq[2][j], ov = gq[3][j];
                float fm = fv + mS[j];
                float mn = fmaxf(fm, iv);
                float ig = __expf(iv - mn);
                float fg = __expf(fm - mn);
                float zc = fminf(fmaxf(zv, -15.f), 15.f);
                float e2 = __expf(2.f * zc);
                float th = (e2 - 1.f) / (e2 + 1.f);
                cS[j] = fg * cS[j] + ig * th;
                nS[j] = fg * nS[j] + ig;
                mS[j] = mn;
                float sg = 1.f / (1.f + __expf(-ov));
                float hv = sg * cS[j] / fmaxf(nS[j], 1e-6f);
                hv8[j] = hv;
                _Float16 hi = (_Float16)hv;
                uh.h[j] = hi;
                ul.h[j] = (_Float16)(hv - (float)hi);
            }

            const size_t tail = (size_t)fkt * 512 + ((size_t)r15 + 16 * fl4s) * 8;
            const size_t feh = (((size_t)((t + 1) & 1) * NC_ + c) * 2 + mt0) * FRAG_MT + tail;
            if (fast) {
                st16_plain(hexFhi + feh, uh.v);
                st16_plain(hexFlo + feh, ul.v);
            } else {
                st16_ic(hexFhi + feh, uh.v);
                st16_ic(hexFlo + feh, ul.v);
            }
            if (!isL2) {
                const size_t fex = (((size_t)t * 4 + g) * 2 + mt0) * FRAG_MT + tail;
                st16_ic(h1Fhi + fex, uh.v);
                if (useH1Lo) st16_ic(h1Flo + fex, ul.v);
            }
            if (isL2 && t == T_ - 1) {
                float* hp = hlast + (size_t)(b0g + mt0 * 16 + r15) * H_ + p * HC_ + o * 8;
                *(float4*)hp       = make_float4(hv8[0], hv8[1], hv8[2], hv8[3]);
                *(float4*)(hp + 4) = make_float4(hv8[4], hv8[5], hv8[6], hv8[7]);
            }

            asm volatile("s_waitcnt vmcnt(0)" ::: "memory");
            if (lane == 0) {
                unsigned nv = (unsigned)(t + 1);
                unsigned* frp = flagR + c * 32 + p;
                if (fast) st4_plain(frp, nv);
                else      ast4(frp, nv);
                if (!isL2) ast4(flagX + c * 32 + p, nv);
            }
        }
    }
}

#define OUT_ 26
__global__ __launch_bounds__(64)
void fc_kernel(const float* __restrict__ hlast, const float* __restrict__ fcw,
               const float* __restrict__ fcb, float* __restrict__ out)
{
    int b = blockIdx.x, oo = threadIdx.x;
    if (oo < OUT_) {
        const float4* hv = reinterpret_cast<const float4*>(hlast + (size_t)b * H_);
        const float4* wv = reinterpret_cast<const float4*>(fcw + (size_t)oo * H_);
        float s = fcb[oo];
        #pragma unroll 4
        for (int k = 0; k < H_ / 4; ++k) {
            float4 h4 = hv[k], w4 = wv[k];
            s += h4.x * w4.x + h4.y * w4.y + h4.z * w4.z + h4.w * w4.w;
        }
        out[(size_t)b * OUT_ + oo] = s;
    }
}

extern "C" void kernel_launch(void* const* d_in, const int* in_sizes, int n_in,
                              void* d_out, int out_size, void* d_ws, size_t ws_size,
                              hipStream_t stream) {
    const float* x   = (const float*)d_in[0];
    const float* W0  = (const float*)d_in[1];
    const float* R0  = (const float*)d_in[2];
    const float* b0  = (const float*)d_in[3];
    const float* W1  = (const float*)d_in[4];
    const float* R1  = (const float*)d_in[5];
    const float* b1  = (const float*)d_in[6];
    const float* fcw = (const float*)d_in[7];
    const float* fcb = (const float*)d_in[8];
    float* out = (float*)d_out;

    if (ws_size < WS_NEED_SMALL) return;
    const int useH1Lo = (ws_size >= WS_NEED_FULL) ? 1 : 0;

    char* ws = (char*)d_ws;
    _Float16* hexFhi = (_Float16*)(ws + WS_HEXHI);
    _Float16* hexFlo = (_Float16*)(ws + WS_HEXLO);
    unsigned* flagR  = (unsigned*)(ws + WS_FLAGR);
    unsigned* flagX  = (unsigned*)(ws + WS_FLAGX);
    unsigned* xccb   = (unsigned*)(ws + WS_XCC);
    unsigned* mech   = (unsigned*)(ws + WS_MECH);
    unsigned* probe  = (unsigned*)(ws + WS_PROBE);
    float*    xTp    = (float*)(ws + WS_XT);
    float*    hlast  = (float*)(ws + WS_HLAST);
    _Float16* h1Fhi  = (_Float16*)(ws + WS_H1HI);
    _Float16* h1Flo  = (_Float16*)(ws + WS_H1LO);

    hipMemsetAsync(ws, 0, WS_ZEROL, stream);
    xt_kernel<<<(B_ * T_ * 3 + 255) / 256, 256, 0, stream>>>(x, xTp);
    fused_slstm<<<NC_ * P_, NW_ * 64, 0, stream>>>(xTp, W0, R0, b0, W1, R1, b1,
                                                   hexFhi, hexFlo, flagR, flagX,
                                                   xccb, mech, probe,
                                                   h1Fhi, h1Flo, hlast, useH1Lo);
    fc_kernel<<<B_, 64, 0, stream>>>(hlast, fcw, fcb, out);
}

// Round 18
// 4550.425 us; speedup vs baseline: 6.4298x; 1.2223x over previous
//
#include <hip/hip_runtime.h>
#include <hip/hip_bf16.h>

typedef _Float16 f16x8 __attribute__((ext_vector_type(8)));
typedef float f32x4 __attribute__((ext_vector_type(4)));
typedef unsigned long long u64;

#define B_   128
#define T_   1024
#define H_   512
#define P_   32
#define HC_  16
#define MB_  32
#define NC_  8
#define NW_  4
#define SPIN_BOUND (1 << 20)

#define FRAG_MT 8192

// ws layout (bytes)
#define WS_HEXHI  0ull
#define WS_HEXLO  524288ull
#define WS_FLAGR  1048576ull      // u32 [NC][32] packed: one 128B line per clique
#define WS_FLAGX  1081344ull      // u32 [4][32] packed
#define WS_XCC    1097728ull
#define WS_MECH   1098752ull
#define WS_PROBE  1099776ull
#define WS_ZEROL  1100800ull
#define WS_XT     1100800ull
#define WS_HLAST  2673664ull
#define WS_H1HI   2935808ull
#define WS_H1LO   137153536ull
#define WS_NEED_SMALL 137153536ull
#define WS_NEED_FULL  271371264ull

#define MFMA(a, b, c) __builtin_amdgcn_mfma_f32_16x16x32_f16((a), (b), (c), 0, 0, 0)

// 16 coalesced dwordx4 loads, ONE vmcnt(0).
#define LD16C(FLAGS, D, DB, P0, P1, P2, P3)                                     \
    asm volatile(                                                               \
        "global_load_dwordx4 %0, %16, off " FLAGS "\n\t"                        \
        "global_load_dwordx4 %1, %16, off offset:1024 " FLAGS "\n\t"            \
        "global_load_dwordx4 %2, %16, off offset:2048 " FLAGS "\n\t"            \
        "global_load_dwordx4 %3, %16, off offset:3072 " FLAGS "\n\t"            \
        "global_load_dwordx4 %4, %17, off " FLAGS "\n\t"                        \
        "global_load_dwordx4 %5, %17, off offset:1024 " FLAGS "\n\t"            \
        "global_load_dwordx4 %6, %17, off offset:2048 " FLAGS "\n\t"            \
        "global_load_dwordx4 %7, %17, off offset:3072 " FLAGS "\n\t"            \
        "global_load_dwordx4 %8, %18, off " FLAGS "\n\t"                        \
        "global_load_dwordx4 %9, %18, off offset:1024 " FLAGS "\n\t"            \
        "global_load_dwordx4 %10, %18, off offset:2048 " FLAGS "\n\t"           \
        "global_load_dwordx4 %11, %18, off offset:3072 " FLAGS "\n\t"           \
        "global_load_dwordx4 %12, %19, off " FLAGS "\n\t"                       \
        "global_load_dwordx4 %13, %19, off offset:1024 " FLAGS "\n\t"           \
        "global_load_dwordx4 %14, %19, off offset:2048 " FLAGS "\n\t"           \
        "global_load_dwordx4 %15, %19, off offset:3072 " FLAGS "\n\t"           \
        "s_waitcnt vmcnt(0)"                                                    \
        : "=&v"(D[0][0]), "=&v"(D[1][0]), "=&v"(D[2][0]), "=&v"(D[3][0]),       \
          "=&v"(D[0][1]), "=&v"(D[1][1]), "=&v"(D[2][1]), "=&v"(D[3][1]),       \
          "=&v"(DB[0][0]), "=&v"(DB[1][0]), "=&v"(DB[2][0]), "=&v"(DB[3][0]),   \
          "=&v"(DB[0][1]), "=&v"(DB[1][1]), "=&v"(DB[2][1]), "=&v"(DB[3][1])    \
        : "v"(P0), "v"(P1), "v"(P2), "v"(P3)                                    \
        : "memory")

__device__ __forceinline__ unsigned ald4(const unsigned* p) {
    return __hip_atomic_load(p, __ATOMIC_RELAXED, __HIP_MEMORY_SCOPE_AGENT);
}
__device__ __forceinline__ void ast4(void* p, unsigned v) {
    __hip_atomic_store((unsigned*)p, v, __ATOMIC_RELAXED, __HIP_MEMORY_SCOPE_AGENT);
}
__device__ __forceinline__ void st4_plain(unsigned* p, unsigned v) {
    asm volatile("global_store_dword %0, %1, off" :: "v"(p), "v"(v) : "memory");
}
__device__ __forceinline__ unsigned ld4_sc1(const unsigned* p) {
    unsigned r;
    asm volatile("global_load_dword %0, %1, off sc1\n\ts_waitcnt vmcnt(0)"
                 : "=v"(r) : "v"(p) : "memory");
    return r;
}
__device__ __forceinline__ void st16_plain(void* p, f16x8 v) {
    asm volatile("global_store_dwordx4 %0, %1, off" :: "v"(p), "v"(v) : "memory");
}
__device__ __forceinline__ void st16_ic(void* p, f16x8 v) {
    asm volatile("global_store_dwordx4 %0, %1, off sc0 sc1" :: "v"(p), "v"(v) : "memory");
}
__device__ __forceinline__ unsigned short f16bits(_Float16 h) {
    union { _Float16 f; unsigned short s; } u; u.f = h; return u.s;
}
__device__ __forceinline__ void heat(unsigned v) {
    float a = (float)(v & 7u) + 1.0f;
    #pragma unroll
    for (int i = 0; i < 16; ++i)
        asm volatile("v_fmac_f32 %0, %1, %2" : "+v"(a) : "v"(1.000001f), "v"(a));
    asm volatile("" :: "v"(a));
}
// partial-buffer chunk swizzle: folds lane bits 3-5 into 0-2. Makes both the
// b128 deposits and the transposed state-phase reads <=2-way bank conflicts.
__device__ __forceinline__ int swz(int cidx) { return cidx ^ ((cidx >> 3) & 7); }

__global__ __launch_bounds__(256)
void xt_kernel(const float* __restrict__ x, float* __restrict__ xT) {
    int idx = blockIdx.x * 256 + threadIdx.x;
    if (idx < B_ * T_ * 3) {
        int d = idx % 3, rest = idx / 3;
        int t = rest % T_, b = rest / T_;
        xT[((size_t)t * B_ + b) * 3 + d] = x[idx];
    }
}

// 256 blocks x 256 threads. LDS: 128KB weights + 2x8KB tree bufs + 2KB stage.
// Per step: MFMA (K-split) -> w1/w3 deposit -> bar -> w2/w0 += -> bar ->
// 256-thread state phase (reads A+B, swizzled) -> tbuf -> bar -> wave0 dense
// stores -> drain -> flags (flagX lagged one step; h1F stores fire-and-forget).
__global__ __launch_bounds__(256, 1)
void fused_slstm(const float* __restrict__ xT,
                 const float* __restrict__ W0, const float* __restrict__ R0,
                 const float* __restrict__ b0v,
                 const float* __restrict__ W1, const float* __restrict__ R1,
                 const float* __restrict__ b1v,
                 _Float16* __restrict__ hexFhi, _Float16* __restrict__ hexFlo,
                 unsigned* __restrict__ flagR, unsigned* __restrict__ flagX,
                 unsigned* __restrict__ xccbuf, unsigned* __restrict__ mech,
                 unsigned* __restrict__ probe,
                 _Float16* __restrict__ h1Fhi, _Float16* __restrict__ h1Flo,
                 float* __restrict__ hlast, int useH1Lo)
{
    constexpr int LDSH = 4 * 16 * 64 * 8;
    __shared__ _Float16 lds[2 * LDSH];
    __shared__ f32x4 bufA[512], bufB[512];     // 8KB each, swizzled chunks
    __shared__ unsigned tbuf32[512];           // 2KB store stage [pl][mt][fl4i][row][j]
    __shared__ int verdLds, mechLds, fastLds;

    const int tid  = threadIdx.x;
    const int lane = tid & 63;
    const int wid  = tid >> 6;
    const int l15  = lane & 15;
    const int l4   = lane >> 4;
    const int kg8  = l4 * 8;
    const int c    = blockIdx.x & 7;
    const int p    = blockIdx.x >> 3;
    const bool isL2 = (c >= 4);
    const int g    = c & 3;
    const int b0g  = g * MB_;

    const float* Rg  = isL2 ? R1 : R0;
    const float* bgp = isL2 ? b1v : b0v;

    // ---- stage weights (frag-major f16), wave wid -> gate q=wid ----
    {
        const int q = wid;
        const int grow = q * H_ + p * HC_ + l15;
        const float* rsrc = Rg + (size_t)grow * H_ + kg8;
        for (int kt = 0; kt < 16; ++kt) {
            const float* s = rsrc + kt * 32;
            _Float16* dhi = &lds[((q * 16 + kt) * 64 + lane) * 8];
            _Float16* dlo = dhi + LDSH;
            if (!isL2) {
                #pragma unroll
                for (int j = 0; j < 8; ++j) {
                    float v = s[j];
                    _Float16 h = (_Float16)v;
                    dhi[j] = h;
                    dlo[j] = (_Float16)(v - (float)h);
                }
            } else {
                const float* ws2 = W1 + (size_t)grow * H_ + kt * 32 + kg8;
                #pragma unroll
                for (int j = 0; j < 8; ++j) {
                    dhi[j] = (_Float16)s[j];
                    dlo[j] = (_Float16)ws2[j];
                }
            }
        }
    }

    // ==== Phase 1: XCC mapping verdict ====
    {
        unsigned myxcc;
        asm volatile("s_getreg_b32 %0, hwreg(20, 0, 32)" : "=s"(myxcc));
        if (tid == 0) ast4(xccbuf + blockIdx.x, 0x100u | (myxcc & 0xFFu));
        if (wid == 0) {
            const unsigned* xp = xccbuf + ((lane & 31) * 8 + c);
            unsigned v = 0;
            int ok = 0;
            for (int it = 0; it < SPIN_BOUND; ++it) {
                v = ald4(xp);
                if (__ballot(v >= 0x100u) == ~0ull) { ok = 1; break; }
                __builtin_amdgcn_s_sleep(2);
            }
            unsigned ref = (unsigned)__shfl((int)v, 0);
            bool alleq = ok && (__ballot((v & 0xFFu) == (ref & 0xFFu)) == ~0ull);
            unsigned o = 0;
            int ok2 = 0;
            const unsigned* op = xccbuf + (c ^ 1);
            for (int it = 0; it < SPIN_BOUND; ++it) {
                o = ald4(op);
                if (o >= 0x100u) { ok2 = 1; break; }
                __builtin_amdgcn_s_sleep(2);
            }
            bool cand = alleq && ok2 && ((o & 0xFFu) != (ref & 0xFFu));
            if (lane == 0) verdLds = cand ? 1 : 0;
        }
    }
    __syncthreads();
    const bool candFast = (verdLds != 0);

    // ==== Phase 2: mechanism probe ====
    if (candFast && p == 0 && tid == 0) {
        for (unsigned k = 1; k <= 3; ++k) {
            st4_plain(probe + c * 32, k);
            asm volatile("s_waitcnt vmcnt(0)" ::: "memory");
            for (int s = 0; s < 32; ++s) __builtin_amdgcn_s_sleep(127);
        }
    }
    if (candFast && wid == 0) {
        unsigned first = 0xFFFFFFFFu;
        int got = 0;
        for (int it = 0; it < (1 << 16); ++it) {
            unsigned v = ld4_sc1(probe + c * 32);
            if (first == 0xFFFFFFFFu) first = v;
            if (v >= 3u) { got = 1; break; }
            __builtin_amdgcn_s_sleep(2);
        }
        if (p != 0 && first >= 3u) got = 0;
        if (lane == 0) mechLds = got;
    }
    __syncthreads();
    const int saw = candFast ? mechLds : 0;

    // ==== Phase 3: consensus ====
    if (tid == 0) ast4(mech + blockIdx.x, 0x100u | (unsigned)(saw & 1));
    if (wid == 0) {
        const unsigned* mp = mech + ((lane & 31) * 8 + c);
        unsigned v = 0;
        int ok = 0;
        for (int it = 0; it < SPIN_BOUND; ++it) {
            v = ald4(mp);
            if (__ballot(v >= 0x100u) == ~0ull) { ok = 1; break; }
            __builtin_amdgcn_s_sleep(2);
        }
        bool allsaw = ok && (__ballot((v & 1u) != 0u) == ~0ull);
        if (lane == 0) fastLds = (candFast && allsaw) ? 1 : 0;
    }

    // ---- per-thread state geometry (ALL 256 threads: 2 elements each) ----
    const int colIdx = tid & 15;
    const int col    = p * HC_ + colIdx;
    const int row0   = tid >> 4;            // 0..15
    float bb[4], w0r[4][3];
    #pragma unroll
    for (int q = 0; q < 4; ++q) bb[q] = bgp[q * H_ + col];
    if (!isL2) {
        #pragma unroll
        for (int q = 0; q < 4; ++q)
            #pragma unroll
            for (int d = 0; d < 3; ++d)
                w0r[q][d] = W0[(size_t)(q * H_ + col) * 3 + d];
    }
    float cS[2] = {0.f, 0.f}, nS[2] = {0.f, 0.f}, mS[2] = {0.f, 0.f};

    const int kt0 = wid * 4;
    int dead = 0;

    __syncthreads();
    const bool fast = (fastLds != 0);

    for (int t = 0; t < T_; ++t) {
        // ---- early x prefetch (L1): consumed at state phase ----
        float xa[2][3];
        if (!isL2) {
            #pragma unroll
            for (int h = 0; h < 2; ++h) {
                const float* xp = xT + ((size_t)t * B_ + b0g + row0 + h * 16) * 3;
                xa[h][0] = xp[0]; xa[h][1] = xp[1]; xa[h][2] = xp[2];
            }
        }

        f32x4 acc[2][4];
        #pragma unroll
        for (int mt = 0; mt < 2; ++mt)
            #pragma unroll
            for (int q = 0; q < 4; ++q) { f32x4 z = {0.f,0.f,0.f,0.f}; acc[mt][q] = z; }

        // ---- L2 feed-forward: poll flagX (lagged), h1F loads + W1 MFMAs ----
        if (isL2) {
            if (!dead) {
                const unsigned* fx = flagX + g * 32 + (lane & 31);
                int it = 0;
                for (;;) {
                    unsigned v = fast ? ld4_sc1(fx) : ald4(fx);
                    if (__ballot(v >= (unsigned)(t + 1)) == ~0ull) break;
                    if (++it > SPIN_BOUND) { dead = 1; break; }
                    heat(v);
                }
            }
            asm volatile("" ::: "memory");
            f16x8 xh[4][2], xhB[4][2];
            const size_t tb = (((size_t)t * 4 + g) * 2) * FRAG_MT + kt0 * 512 + lane * 8;
            const _Float16* q0 = h1Fhi + tb;
            const _Float16* q1 = h1Fhi + tb + FRAG_MT;
            if (useH1Lo) {
                const _Float16* q2 = h1Flo + tb;
                const _Float16* q3 = h1Flo + tb + FRAG_MT;
                LD16C("sc0 sc1", xh, xhB, q0, q1, q2, q3);
            } else {
                asm volatile(
                    "global_load_dwordx4 %0, %8, off sc0 sc1\n\t"
                    "global_load_dwordx4 %1, %8, off offset:1024 sc0 sc1\n\t"
                    "global_load_dwordx4 %2, %8, off offset:2048 sc0 sc1\n\t"
                    "global_load_dwordx4 %3, %8, off offset:3072 sc0 sc1\n\t"
                    "global_load_dwordx4 %4, %9, off sc0 sc1\n\t"
                    "global_load_dwordx4 %5, %9, off offset:1024 sc0 sc1\n\t"
                    "global_load_dwordx4 %6, %9, off offset:2048 sc0 sc1\n\t"
                    "global_load_dwordx4 %7, %9, off offset:3072 sc0 sc1\n\t"
                    "s_waitcnt vmcnt(0)"
                    : "=&v"(xh[0][0]), "=&v"(xh[1][0]), "=&v"(xh[2][0]), "=&v"(xh[3][0]),
                      "=&v"(xh[0][1]), "=&v"(xh[1][1]), "=&v"(xh[2][1]), "=&v"(xh[3][1])
                    : "v"(q0), "v"(q1)
                    : "memory");
            }
            #pragma unroll
            for (int k = 0; k < 4; ++k)
                #pragma unroll
                for (int q = 0; q < 4; ++q) {
                    f16x8 w = *(const f16x8*)&lds[LDSH + ((q * 16 + kt0 + k) * 64 + lane) * 8];
                    acc[0][q] = MFMA(xh[k][0], w, acc[0][q]);
                    acc[1][q] = MFMA(xh[k][1], w, acc[1][q]);
                    if (useH1Lo) {
                        acc[0][q] = MFMA(xhB[k][0], w, acc[0][q]);
                        acc[1][q] = MFMA(xhB[k][1], w, acc[1][q]);
                    }
                }
        }

        // ---- recurrent wait: packed-line poll ----
        if (t > 0 && !dead) {
            const unsigned* fr = flagR + c * 32 + (lane & 31);
            int it = 0;
            for (;;) {
                unsigned v = fast ? ld4_sc1(fr) : ald4(fr);
                if (__ballot(v >= (unsigned)t) == ~0ull) break;
                if (++it > SPIN_BOUND) { dead = 1; break; }
                heat(v);
            }
            asm volatile("" ::: "memory");
        }

        // ---- recurrent A-frags (coalesced) + MFMAs ----
        f16x8 ah[4][2], ahB[4][2];
        {
            const size_t hb = (((size_t)(t & 1) * NC_ + c) * 2) * FRAG_MT + kt0 * 512 + lane * 8;
            const _Float16* ph0 = hexFhi + hb;
            const _Float16* ph1 = hexFhi + hb + FRAG_MT;
            const _Float16* pl0 = hexFlo + hb;
            const _Float16* pl1 = hexFlo + hb + FRAG_MT;
            if (fast) { LD16C("sc1", ah, ahB, ph0, ph1, pl0, pl1); }
            else      { LD16C("sc0 sc1", ah, ahB, ph0, ph1, pl0, pl1); }
        }
        #pragma unroll
        for (int k = 0; k < 4; ++k)
            #pragma unroll
            for (int q = 0; q < 4; ++q) {
                f16x8 rh = *(const f16x8*)&lds[((q * 16 + kt0 + k) * 64 + lane) * 8];
                acc[0][q] = MFMA(ah[k][0], rh, acc[0][q]);
                acc[1][q] = MFMA(ah[k][1], rh, acc[1][q]);
                acc[0][q] = MFMA(ahB[k][0], rh, acc[0][q]);
                acc[1][q] = MFMA(ahB[k][1], rh, acc[1][q]);
                if (!isL2) {
                    f16x8 rlo = *(const f16x8*)&lds[LDSH + ((q * 16 + kt0 + k) * 64 + lane) * 8];
                    acc[0][q] = MFMA(ah[k][0], rlo, acc[0][q]);
                    acc[1][q] = MFMA(ah[k][1], rlo, acc[1][q]);
                }
            }

        // ---- pairwise tree reduce (swizzled, no atomics, no serial chain) ----
        if (wid == 1) {
            #pragma unroll
            for (int mt = 0; mt < 2; ++mt)
                #pragma unroll
                for (int q = 0; q < 4; ++q)
                    bufA[swz((mt * 4 + q) * 64 + lane)] = acc[mt][q];
        } else if (wid == 3) {
            #pragma unroll
            for (int mt = 0; mt < 2; ++mt)
                #pragma unroll
                for (int q = 0; q < 4; ++q)
                    bufB[swz((mt * 4 + q) * 64 + lane)] = acc[mt][q];
        }
        __syncthreads();                       // bar1
        if (wid == 2) {
            #pragma unroll
            for (int mt = 0; mt < 2; ++mt)
                #pragma unroll
                for (int q = 0; q < 4; ++q) {
                    const int s = swz((mt * 4 + q) * 64 + lane);
                    f32x4 v = bufA[s]; v += acc[mt][q]; bufA[s] = v;
                }
        } else if (wid == 0) {
            #pragma unroll
            for (int mt = 0; mt < 2; ++mt)
                #pragma unroll
                for (int q = 0; q < 4; ++q) {
                    const int s = swz((mt * 4 + q) * 64 + lane);
                    f32x4 v = bufB[s]; v += acc[mt][q]; bufB[s] = v;
                }
        }
        __syncthreads();                       // bar2

        // ---- distributed state phase: 256 threads x 2 elements ----
        const float* fA = (const float*)bufA;
        const float* fB = (const float*)bufB;
        unsigned pk[2][2];
        #pragma unroll
        for (int h = 0; h < 2; ++h) {
            float gq[4];
            #pragma unroll
            for (int q = 0; q < 4; ++q) {
                const int cidx = (h * 4 + q) * 64 + (row0 >> 2) * 16 + colIdx;
                const int w = swz(cidx) * 4 + (row0 & 3);
                float e = fA[w] + fB[w] + bb[q];
                if (!isL2)
                    e += w0r[q][0]*xa[h][0] + w0r[q][1]*xa[h][1] + w0r[q][2]*xa[h][2];
                gq[q] = e;
            }
            float iv = gq[0], fv = gq[1], zv = gq[2], ov = gq[3];
            float fm = fv + mS[h];
            float mn = fmaxf(fm, iv);
            float ig = __expf(iv - mn);
            float fg = __expf(fm - mn);
            float zc = fminf(fmaxf(zv, -15.f), 15.f);
            float e2 = __expf(2.f * zc);
            float th = (e2 - 1.f) / (e2 + 1.f);
            cS[h] = fg * cS[h] + ig * th;
            nS[h] = fg * nS[h] + ig;
            mS[h] = mn;
            float sg = 1.f / (1.f + __expf(-ov));
            float hv = sg * cS[h] / fmaxf(nS[h], 1e-6f);

            if (isL2 && t == T_ - 1)
                hlast[(size_t)(b0g + row0 + h * 16) * H_ + col] = hv;

            _Float16 hi = (_Float16)hv;
            _Float16 lo = (_Float16)(hv - (float)hi);
            unsigned self = (unsigned)f16bits(hi) | ((unsigned)f16bits(lo) << 16);
            unsigned part = (unsigned)__shfl_xor((int)self, 1);
            pk[h][0] = (self & 0xffffu) | ((part & 0xffffu) << 16);   // hi pair
            pk[h][1] = (self >> 16) | (part & 0xffff0000u);           // lo pair
        }

        // ---- stage packed pairs into tbuf [pl][mt][fl4i][row][j] ----
        if (!(colIdx & 1)) {
            const int fl4i = colIdx >> 3;
            const int cj   = (colIdx & 7) >> 1;
            #pragma unroll
            for (int h = 0; h < 2; ++h) {
                #pragma unroll
                for (int pl = 0; pl < 2; ++pl)
                    tbuf32[(((pl * 2 + h) * 2 + fl4i) * 16 + row0) * 4 + cj] = pk[h][pl];
            }
        }
        __syncthreads();                       // bar3

        // ---- wave0: dense frag stores + drain + flags ----
        if (wid == 0) {
            const f16x8* tv = (const f16x8*)tbuf32;
            f16x8 vh = tv[lane];          // hi plane chunk
            f16x8 vl = tv[64 + lane];     // lo plane chunk
            const int mt   = lane >> 5;
            const int fl4i = (lane >> 4) & 1;
            const int row  = lane & 15;
            const int flg  = row + 16 * ((p & 1) * 2 + fl4i);
            const size_t tail = (size_t)(p >> 1) * 512 + (size_t)flg * 8;
            const size_t feh = (((size_t)((t + 1) & 1) * NC_ + c) * 2 + mt) * FRAG_MT + tail;
            if (fast) {
                st16_plain(hexFhi + feh, vh);
                st16_plain(hexFlo + feh, vl);
            } else {
                st16_ic(hexFhi + feh, vh);
                st16_ic(hexFlo + feh, vl);
            }
            asm volatile("s_waitcnt vmcnt(0)" ::: "memory");
            if (lane == 0) {
                unsigned* frp = flagR + c * 32 + p;
                if (fast) st4_plain(frp, (unsigned)(t + 1));
                else      ast4(frp, (unsigned)(t + 1));
                if (!isL2) ast4(flagX + c * 32 + p, (unsigned)t);   // lagged: covers h1F[t-1]
            }
            if (!isL2) {                  // fire-and-forget; drained by next step's vmcnt(0)
                const size_t fex = (((size_t)t * 4 + g) * 2 + mt) * FRAG_MT + tail;
                st16_ic(h1Fhi + fex, vh);
                if (useH1Lo) st16_ic(h1Flo + fex, vl);
            }
        }
    }

    // ---- post-loop (L1): drain h1F tail, publish final flagX ----
    if (!isL2) {
        asm volatile("s_waitcnt vmcnt(0)" ::: "memory");
        __syncthreads();
        if (tid == 0) ast4(flagX + c * 32 + p, (unsigned)(T_ + 1));
    }
}

#define OUT_ 26
__global__ __launch_bounds__(64)
void fc_kernel(const float* __restrict__ hlast, const float* __restrict__ fcw,
               const float* __restrict__ fcb, float* __restrict__ out)
{
    int b = blockIdx.x, oo = threadIdx.x;
    if (oo < OUT_) {
        const float4* hv = reinterpret_cast<const float4*>(hlast + (size_t)b * H_);
        const float4* wv = reinterpret_cast<const float4*>(fcw + (size_t)oo * H_);
        float s = fcb[oo];
        #pragma unroll 4
        for (int k = 0; k < H_ / 4; ++k) {
            float4 h4 = hv[k], w4 = wv[k];
            s += h4.x * w4.x + h4.y * w4.y + h4.z * w4.z + h4.w * w4.w;
        }
        out[(size_t)b * OUT_ + oo] = s;
    }
}

extern "C" void kernel_launch(void* const* d_in, const int* in_sizes, int n_in,
                              void* d_out, int out_size, void* d_ws, size_t ws_size,
                              hipStream_t stream) {
    const float* x   = (const float*)d_in[0];
    const float* W0  = (const float*)d_in[1];
    const float* R0  = (const float*)d_in[2];
    const float* b0  = (const float*)d_in[3];
    const float* W1  = (const float*)d_in[4];
    const float* R1  = (const float*)d_in[5];
    const float* b1  = (const float*)d_in[6];
    const float* fcw = (const float*)d_in[7];
    const float* fcb = (const float*)d_in[8];
    float* out = (float*)d_out;

    if (ws_size < WS_NEED_SMALL) return;
    const int useH1Lo = (ws_size >= WS_NEED_FULL) ? 1 : 0;

    char* ws = (char*)d_ws;
    _Float16* hexFhi = (_Float16*)(ws + WS_HEXHI);
    _Float16* hexFlo = (_Float16*)(ws + WS_HEXLO);
    unsigned* flagR  = (unsigned*)(ws + WS_FLAGR);
    unsigned* flagX  = (unsigned*)(ws + WS_FLAGX);
    unsigned* xccb   = (unsigned*)(ws + WS_XCC);
    unsigned* mech   = (unsigned*)(ws + WS_MECH);
    unsigned* probe  = (unsigned*)(ws + WS_PROBE);
    float*    xTp    = (float*)(ws + WS_XT);
    float*    hlast  = (float*)(ws + WS_HLAST);
    _Float16* h1Fhi  = (_Float16*)(ws + WS_H1HI);
    _Float16* h1Flo  = (_Float16*)(ws + WS_H1LO);

    hipMemsetAsync(ws, 0, WS_ZEROL, stream);
    xt_kernel<<<(B_ * T_ * 3 + 255) / 256, 256, 0, stream>>>(x, xTp);
    fused_slstm<<<NC_ * P_, NW_ * 64, 0, stream>>>(xTp, W0, R0, b0, W1, R1, b1,
                                                   hexFhi, hexFlo, flagR, flagX,
                                                   xccb, mech, probe,
                                                   h1Fhi, h1Flo, hlast, useH1Lo);
    fc_kernel<<<B_, 64, 0, stream>>>(hlast, fcw, fcb, out);
}

// Round 19
// 3817.809 us; speedup vs baseline: 7.6636x; 1.1919x over previous
//
#include <hip/hip_runtime.h>
#include <hip/hip_bf16.h>

typedef _Float16 f16x8 __attribute__((ext_vector_type(8)));
typedef float f32x4 __attribute__((ext_vector_type(4)));
typedef unsigned long long u64;

#define B_   128
#define T_   1024
#define H_   512
#define P_   32
#define HC_  16
#define MB_  32
#define NC_  8
#define NW_  4
#define SPIN_BOUND (1 << 20)

#define FRAG_MT 8192

// ws layout (bytes) — lo planes retained in layout but UNUSED (single-plane f16
// exchange this round; spends accuracy margin: baseline 1.95e-3 vs thr 6.875e-3)
#define WS_HEXHI  0ull
#define WS_HEXLO  524288ull
#define WS_FLAGR  1048576ull      // u32 [NC][32] packed: one 128B line per clique
#define WS_FLAGX  1081344ull      // u32 [4][32] packed
#define WS_XCC    1097728ull
#define WS_MECH   1098752ull
#define WS_PROBE  1099776ull
#define WS_ZEROL  1100800ull
#define WS_XT     1100800ull
#define WS_HLAST  2673664ull
#define WS_H1HI   2935808ull
#define WS_H1LO   137153536ull
#define WS_NEED_SMALL 137153536ull

#define MFMA(a, b, c) __builtin_amdgcn_mfma_f32_16x16x32_f16((a), (b), (c), 0, 0, 0)

// 8 coalesced dwordx4 loads (2 bases x 4 kt-chunks), ONE vmcnt(0).
#define LD8C(FLAGS, D, P0, P1)                                                  \
    asm volatile(                                                               \
        "global_load_dwordx4 %0, %8, off " FLAGS "\n\t"                         \
        "global_load_dwordx4 %1, %8, off offset:1024 " FLAGS "\n\t"             \
        "global_load_dwordx4 %2, %8, off offset:2048 " FLAGS "\n\t"             \
        "global_load_dwordx4 %3, %8, off offset:3072 " FLAGS "\n\t"             \
        "global_load_dwordx4 %4, %9, off " FLAGS "\n\t"                         \
        "global_load_dwordx4 %5, %9, off offset:1024 " FLAGS "\n\t"             \
        "global_load_dwordx4 %6, %9, off offset:2048 " FLAGS "\n\t"             \
        "global_load_dwordx4 %7, %9, off offset:3072 " FLAGS "\n\t"             \
        "s_waitcnt vmcnt(0)"                                                    \
        : "=&v"(D[0][0]), "=&v"(D[1][0]), "=&v"(D[2][0]), "=&v"(D[3][0]),       \
          "=&v"(D[0][1]), "=&v"(D[1][1]), "=&v"(D[2][1]), "=&v"(D[3][1])        \
        : "v"(P0), "v"(P1)                                                      \
        : "memory")

__device__ __forceinline__ unsigned ald4(const unsigned* p) {
    return __hip_atomic_load(p, __ATOMIC_RELAXED, __HIP_MEMORY_SCOPE_AGENT);
}
__device__ __forceinline__ void ast4(void* p, unsigned v) {
    __hip_atomic_store((unsigned*)p, v, __ATOMIC_RELAXED, __HIP_MEMORY_SCOPE_AGENT);
}
__device__ __forceinline__ void st4_plain(unsigned* p, unsigned v) {
    asm volatile("global_store_dword %0, %1, off" :: "v"(p), "v"(v) : "memory");
}
__device__ __forceinline__ unsigned ld4_sc1(const unsigned* p) {
    unsigned r;
    asm volatile("global_load_dword %0, %1, off sc1\n\ts_waitcnt vmcnt(0)"
                 : "=v"(r) : "v"(p) : "memory");
    return r;
}
__device__ __forceinline__ void st16_plain(void* p, f16x8 v) {
    asm volatile("global_store_dwordx4 %0, %1, off" :: "v"(p), "v"(v) : "memory");
}
__device__ __forceinline__ void st16_ic(void* p, f16x8 v) {
    asm volatile("global_store_dwordx4 %0, %1, off sc0 sc1" :: "v"(p), "v"(v) : "memory");
}
__device__ __forceinline__ unsigned short f16bits(_Float16 h) {
    union { _Float16 f; unsigned short s; } u; u.f = h; return u.s;
}
__device__ __forceinline__ void heat(unsigned v) {
    float a = (float)(v & 7u) + 1.0f;
    #pragma unroll
    for (int i = 0; i < 16; ++i)
        asm volatile("v_fmac_f32 %0, %1, %2" : "+v"(a) : "v"(1.000001f), "v"(a));
    asm volatile("" :: "v"(a));
}
// partial-buffer chunk swizzle (r18): deposits and transposed reads <=2-way.
__device__ __forceinline__ int swz(int cidx) { return cidx ^ ((cidx >> 3) & 7); }

__global__ __launch_bounds__(256)
void xt_kernel(const float* __restrict__ x, float* __restrict__ xT) {
    int idx = blockIdx.x * 256 + threadIdx.x;
    if (idx < B_ * T_ * 3) {
        int d = idx % 3, rest = idx / 3;
        int t = rest % T_, b = rest / T_;
        xT[((size_t)t * B_ + b) * 3 + d] = x[idx];
    }
}

// 256 blocks x 256 threads. Single-plane f16 exchange; weights stay hi/lo.
__global__ __launch_bounds__(256, 1)
void fused_slstm(const float* __restrict__ xT,
                 const float* __restrict__ W0, const float* __restrict__ R0,
                 const float* __restrict__ b0v,
                 const float* __restrict__ W1, const float* __restrict__ R1,
                 const float* __restrict__ b1v,
                 _Float16* __restrict__ hexFhi, _Float16* __restrict__ hexFlo,
                 unsigned* __restrict__ flagR, unsigned* __restrict__ flagX,
                 unsigned* __restrict__ xccbuf, unsigned* __restrict__ mech,
                 unsigned* __restrict__ probe,
                 _Float16* __restrict__ h1Fhi, _Float16* __restrict__ h1Flo,
                 float* __restrict__ hlast)
{
    constexpr int LDSH = 4 * 16 * 64 * 8;
    __shared__ _Float16 lds[2 * LDSH];
    __shared__ f32x4 bufA[512], bufB[512];     // 8KB each, swizzled chunks
    __shared__ unsigned tbuf32[256];           // 1KB store stage [mt][fl4i][row][cj]
    __shared__ int verdLds, mechLds, fastLds;

    const int tid  = threadIdx.x;
    const int lane = tid & 63;
    const int wid  = tid >> 6;
    const int l15  = lane & 15;
    const int l4   = lane >> 4;
    const int kg8  = l4 * 8;
    const int c    = blockIdx.x & 7;
    const int p    = blockIdx.x >> 3;
    const bool isL2 = (c >= 4);
    const int g    = c & 3;
    const int b0g  = g * MB_;

    const float* Rg  = isL2 ? R1 : R0;
    const float* bgp = isL2 ? b1v : b0v;

    // ---- stage weights (frag-major f16), wave wid -> gate q=wid ----
    {
        const int q = wid;
        const int grow = q * H_ + p * HC_ + l15;
        const float* rsrc = Rg + (size_t)grow * H_ + kg8;
        for (int kt = 0; kt < 16; ++kt) {
            const float* s = rsrc + kt * 32;
            _Float16* dhi = &lds[((q * 16 + kt) * 64 + lane) * 8];
            _Float16* dlo = dhi + LDSH;
            if (!isL2) {
                #pragma unroll
                for (int j = 0; j < 8; ++j) {
                    float v = s[j];
                    _Float16 h = (_Float16)v;
                    dhi[j] = h;
                    dlo[j] = (_Float16)(v - (float)h);   // R0_lo
                }
            } else {
                const float* ws2 = W1 + (size_t)grow * H_ + kt * 32 + kg8;
                #pragma unroll
                for (int j = 0; j < 8; ++j) {
                    dhi[j] = (_Float16)s[j];             // R1_hi
                    dlo[j] = (_Float16)ws2[j];           // W1_hi
                }
            }
        }
    }

    // ==== Phase 1: XCC mapping verdict ====
    {
        unsigned myxcc;
        asm volatile("s_getreg_b32 %0, hwreg(20, 0, 32)" : "=s"(myxcc));
        if (tid == 0) ast4(xccbuf + blockIdx.x, 0x100u | (myxcc & 0xFFu));
        if (wid == 0) {
            const unsigned* xp = xccbuf + ((lane & 31) * 8 + c);
            unsigned v = 0;
            int ok = 0;
            for (int it = 0; it < SPIN_BOUND; ++it) {
                v = ald4(xp);
                if (__ballot(v >= 0x100u) == ~0ull) { ok = 1; break; }
                __builtin_amdgcn_s_sleep(2);
            }
            unsigned ref = (unsigned)__shfl((int)v, 0);
            bool alleq = ok && (__ballot((v & 0xFFu) == (ref & 0xFFu)) == ~0ull);
            unsigned o = 0;
            int ok2 = 0;
            const unsigned* op = xccbuf + (c ^ 1);
            for (int it = 0; it < SPIN_BOUND; ++it) {
                o = ald4(op);
                if (o >= 0x100u) { ok2 = 1; break; }
                __builtin_amdgcn_s_sleep(2);
            }
            bool cand = alleq && ok2 && ((o & 0xFFu) != (ref & 0xFFu));
            if (lane == 0) verdLds = cand ? 1 : 0;
        }
    }
    __syncthreads();
    const bool candFast = (verdLds != 0);

    // ==== Phase 2: mechanism probe ====
    if (candFast && p == 0 && tid == 0) {
        for (unsigned k = 1; k <= 3; ++k) {
            st4_plain(probe + c * 32, k);
            asm volatile("s_waitcnt vmcnt(0)" ::: "memory");
            for (int s = 0; s < 32; ++s) __builtin_amdgcn_s_sleep(127);
        }
    }
    if (candFast && wid == 0) {
        unsigned first = 0xFFFFFFFFu;
        int got = 0;
        for (int it = 0; it < (1 << 16); ++it) {
            unsigned v = ld4_sc1(probe + c * 32);
            if (first == 0xFFFFFFFFu) first = v;
            if (v >= 3u) { got = 1; break; }
            __builtin_amdgcn_s_sleep(2);
        }
        if (p != 0 && first >= 3u) got = 0;
        if (lane == 0) mechLds = got;
    }
    __syncthreads();
    const int saw = candFast ? mechLds : 0;

    // ==== Phase 3: consensus ====
    if (tid == 0) ast4(mech + blockIdx.x, 0x100u | (unsigned)(saw & 1));
    if (wid == 0) {
        const unsigned* mp = mech + ((lane & 31) * 8 + c);
        unsigned v = 0;
        int ok = 0;
        for (int it = 0; it < SPIN_BOUND; ++it) {
            v = ald4(mp);
            if (__ballot(v >= 0x100u) == ~0ull) { ok = 1; break; }
            __builtin_amdgcn_s_sleep(2);
        }
        bool allsaw = ok && (__ballot((v & 1u) != 0u) == ~0ull);
        if (lane == 0) fastLds = (candFast && allsaw) ? 1 : 0;
    }

    // ---- per-thread state geometry (all 256 threads: 2 elements each) ----
    const int colIdx = tid & 15;
    const int col    = p * HC_ + colIdx;
    const int row0   = tid >> 4;
    float bb[4], w0r[4][3];
    #pragma unroll
    for (int q = 0; q < 4; ++q) bb[q] = bgp[q * H_ + col];
    if (!isL2) {
        #pragma unroll
        for (int q = 0; q < 4; ++q)
            #pragma unroll
            for (int d = 0; d < 3; ++d)
                w0r[q][d] = W0[(size_t)(q * H_ + col) * 3 + d];
    }
    float cS[2] = {0.f, 0.f}, nS[2] = {0.f, 0.f}, mS[2] = {0.f, 0.f};

    const int kt0 = wid * 4;
    int dead = 0;

    __syncthreads();
    const bool fast = (fastLds != 0);

    for (int t = 0; t < T_; ++t) {
        float xa[2][3];
        if (!isL2) {
            #pragma unroll
            for (int h = 0; h < 2; ++h) {
                const float* xp = xT + ((size_t)t * B_ + b0g + row0 + h * 16) * 3;
                xa[h][0] = xp[0]; xa[h][1] = xp[1]; xa[h][2] = xp[2];
            }
        }

        f32x4 acc[2][4];
        #pragma unroll
        for (int mt = 0; mt < 2; ++mt)
            #pragma unroll
            for (int q = 0; q < 4; ++q) { f32x4 z = {0.f,0.f,0.f,0.f}; acc[mt][q] = z; }

        // ---- L2 feed-forward: poll flagX (lagged), 8 h1F loads + 16 MFMA ----
        if (isL2) {
            if (!dead) {
                const unsigned* fx = flagX + g * 32 + (lane & 31);
                int it = 0;
                for (;;) {
                    unsigned v = fast ? ld4_sc1(fx) : ald4(fx);
                    if (__ballot(v >= (unsigned)(t + 1)) == ~0ull) break;
                    if (++it > SPIN_BOUND) { dead = 1; break; }
                    heat(v);
                }
            }
            asm volatile("" ::: "memory");
            f16x8 xh[4][2];
            const size_t tb = (((size_t)t * 4 + g) * 2) * FRAG_MT + kt0 * 512 + lane * 8;
            const _Float16* q0 = h1Fhi + tb;
            const _Float16* q1 = h1Fhi + tb + FRAG_MT;
            LD8C("sc0 sc1", xh, q0, q1);
            #pragma unroll
            for (int k = 0; k < 4; ++k)
                #pragma unroll
                for (int q = 0; q < 4; ++q) {
                    f16x8 w = *(const f16x8*)&lds[LDSH + ((q * 16 + kt0 + k) * 64 + lane) * 8];
                    acc[0][q] = MFMA(xh[k][0], w, acc[0][q]);
                    acc[1][q] = MFMA(xh[k][1], w, acc[1][q]);
                }
        }

        // ---- recurrent wait: packed-line poll ----
        if (t > 0 && !dead) {
            const unsigned* fr = flagR + c * 32 + (lane & 31);
            int it = 0;
            for (;;) {
                unsigned v = fast ? ld4_sc1(fr) : ald4(fr);
                if (__ballot(v >= (unsigned)t) == ~0ull) break;
                if (++it > SPIN_BOUND) { dead = 1; break; }
                heat(v);
            }
            asm volatile("" ::: "memory");
        }

        // ---- recurrent A-frags (8 coalesced loads) + MFMAs ----
        f16x8 ah[4][2];
        {
            const size_t hb = (((size_t)(t & 1) * NC_ + c) * 2) * FRAG_MT + kt0 * 512 + lane * 8;
            const _Float16* ph0 = hexFhi + hb;
            const _Float16* ph1 = hexFhi + hb + FRAG_MT;
            if (fast) { LD8C("sc1", ah, ph0, ph1); }
            else      { LD8C("sc0 sc1", ah, ph0, ph1); }
        }
        #pragma unroll
        for (int k = 0; k < 4; ++k)
            #pragma unroll
            for (int q = 0; q < 4; ++q) {
                f16x8 rh = *(const f16x8*)&lds[((q * 16 + kt0 + k) * 64 + lane) * 8];
                acc[0][q] = MFMA(ah[k][0], rh, acc[0][q]);
                acc[1][q] = MFMA(ah[k][1], rh, acc[1][q]);
                if (!isL2) {      // h x R0_lo (weight-precision compensation)
                    f16x8 rlo = *(const f16x8*)&lds[LDSH + ((q * 16 + kt0 + k) * 64 + lane) * 8];
                    acc[0][q] = MFMA(ah[k][0], rlo, acc[0][q]);
                    acc[1][q] = MFMA(ah[k][1], rlo, acc[1][q]);
                }
            }

        // ---- pairwise tree reduce (swizzled, atomic-free) ----
        if (wid == 1) {
            #pragma unroll
            for (int mt = 0; mt < 2; ++mt)
                #pragma unroll
                for (int q = 0; q < 4; ++q)
                    bufA[swz((mt * 4 + q) * 64 + lane)] = acc[mt][q];
        } else if (wid == 3) {
            #pragma unroll
            for (int mt = 0; mt < 2; ++mt)
                #pragma unroll
                for (int q = 0; q < 4; ++q)
                    bufB[swz((mt * 4 + q) * 64 + lane)] = acc[mt][q];
        }
        __syncthreads();                       // bar1
        if (wid == 2) {
            #pragma unroll
            for (int mt = 0; mt < 2; ++mt)
                #pragma unroll
                for (int q = 0; q < 4; ++q) {
                    const int s = swz((mt * 4 + q) * 64 + lane);
                    f32x4 v = bufA[s]; v += acc[mt][q]; bufA[s] = v;
                }
        } else if (wid == 0) {
            #pragma unroll
            for (int mt = 0; mt < 2; ++mt)
                #pragma unroll
                for (int q = 0; q < 4; ++q) {
                    const int s = swz((mt * 4 + q) * 64 + lane);
                    f32x4 v = bufB[s]; v += acc[mt][q]; bufB[s] = v;
                }
        }
        __syncthreads();                       // bar2

        // ---- distributed state phase: 256 threads x 2 elements ----
        const float* fA = (const float*)bufA;
        const float* fB = (const float*)bufB;
        unsigned pk[2];
        #pragma unroll
        for (int h = 0; h < 2; ++h) {
            float gq[4];
            #pragma unroll
            for (int q = 0; q < 4; ++q) {
                const int cidx = (h * 4 + q) * 64 + (row0 >> 2) * 16 + colIdx;
                const int w = swz(cidx) * 4 + (row0 & 3);
                float e = fA[w] + fB[w] + bb[q];
                if (!isL2)
                    e += w0r[q][0]*xa[h][0] + w0r[q][1]*xa[h][1] + w0r[q][2]*xa[h][2];
                gq[q] = e;
            }
            float iv = gq[0], fv = gq[1], zv = gq[2], ov = gq[3];
            float fm = fv + mS[h];
            float mn = fmaxf(fm, iv);
            float ig = __expf(iv - mn);
            float fg = __expf(fm - mn);
            float zc = fminf(fmaxf(zv, -15.f), 15.f);
            float e2 = __expf(2.f * zc);
            float th = (e2 - 1.f) / (e2 + 1.f);
            cS[h] = fg * cS[h] + ig * th;
            nS[h] = fg * nS[h] + ig;
            mS[h] = mn;
            float sg = 1.f / (1.f + __expf(-ov));
            float hv = sg * cS[h] / fmaxf(nS[h], 1e-6f);

            if (isL2 && t == T_ - 1)
                hlast[(size_t)(b0g + row0 + h * 16) * H_ + col] = hv;

            unsigned self = (unsigned)f16bits((_Float16)hv);
            unsigned part = (unsigned)__shfl_xor((int)(self << 16), 1) >> 16;
            // even lane keeps (self, partner) packed
            pk[h] = (self & 0xffffu) | ((unsigned)part << 16);
        }

        // ---- stage packed pairs into tbuf [h][fl4i][row][cj] ----
        if (!(colIdx & 1)) {
            const int fl4i = colIdx >> 3;
            const int cj   = (colIdx & 7) >> 1;
            #pragma unroll
            for (int h = 0; h < 2; ++h)
                tbuf32[((h * 2 + fl4i) * 16 + row0) * 4 + cj] = pk[h];
        }
        __syncthreads();                       // bar3

        // ---- wave0: dense frag stores + drain + flags ----
        if (wid == 0) {
            const f16x8* tv = (const f16x8*)tbuf32;
            f16x8 vh = tv[lane & 63];
            const int mt   = lane >> 5;
            const int fl4i = (lane >> 4) & 1;
            const int row  = lane & 15;
            const int flg  = row + 16 * ((p & 1) * 2 + fl4i);
            const size_t tail = (size_t)(p >> 1) * 512 + (size_t)flg * 8;
            const size_t feh = (((size_t)((t + 1) & 1) * NC_ + c) * 2 + mt) * FRAG_MT + tail;
            if (fast) st16_plain(hexFhi + feh, vh);
            else      st16_ic(hexFhi + feh, vh);
            asm volatile("s_waitcnt vmcnt(0)" ::: "memory");
            if (lane == 0) {
                unsigned* frp = flagR + c * 32 + p;
                if (fast) st4_plain(frp, (unsigned)(t + 1));
                else      ast4(frp, (unsigned)(t + 1));
                if (!isL2) ast4(flagX + c * 32 + p, (unsigned)t);   // lagged
            }
            if (!isL2) {                 // fire-and-forget; next step's vmcnt drains
                const size_t fex = (((size_t)t * 4 + g) * 2 + mt) * FRAG_MT + tail;
                st16_ic(h1Fhi + fex, vh);
            }
        }
    }

    // ---- post-loop (L1): drain h1F tail, publish final flagX ----
    if (!isL2) {
        asm volatile("s_waitcnt vmcnt(0)" ::: "memory");
        __syncthreads();
        if (tid == 0) ast4(flagX + c * 32 + p, (unsigned)(T_ + 1));
    }
}

#define OUT_ 26
__global__ __launch_bounds__(64)
void fc_kernel(const float* __restrict__ hlast, const float* __restrict__ fcw,
               const float* __restrict__ fcb, float* __restrict__ out)
{
    int b = blockIdx.x, oo = threadIdx.x;
    if (oo < OUT_) {
        const float4* hv = reinterpret_cast<const float4*>(hlast + (size_t)b * H_);
        const float4* wv = reinterpret_cast<const float4*>(fcw + (size_t)oo * H_);
        float s = fcb[oo];
        #pragma unroll 4
        for (int k = 0; k < H_ / 4; ++k) {
            float4 h4 = hv[k], w4 = wv[k];
            s += h4.x * w4.x + h4.y * w4.y + h4.z * w4.z + h4.w * w4.w;
        }
        out[(size_t)b * OUT_ + oo] = s;
    }
}

extern "C" void kernel_launch(void* const* d_in, const int* in_sizes, int n_in,
                              void* d_out, int out_size, void* d_ws, size_t ws_size,
                              hipStream_t stream) {
    const float* x   = (const float*)d_in[0];
    const float* W0  = (const float*)d_in[1];
    const float* R0  = (const float*)d_in[2];
    const float* b0  = (const float*)d_in[3];
    const float* W1  = (const float*)d_in[4];
    const float* R1  = (const float*)d_in[5];
    const float* b1  = (const float*)d_in[6];
    const float* fcw = (const float*)d_in[7];
    const float* fcb = (const float*)d_in[8];
    float* out = (float*)d_out;

    if (ws_size < WS_NEED_SMALL) return;

    char* ws = (char*)d_ws;
    _Float16* hexFhi = (_Float16*)(ws + WS_HEXHI);
    _Float16* hexFlo = (_Float16*)(ws + WS_HEXLO);
    unsigned* flagR  = (unsigned*)(ws + WS_FLAGR);
    unsigned* flagX  = (unsigned*)(ws + WS_FLAGX);
    unsigned* xccb   = (unsigned*)(ws + WS_XCC);
    unsigned* mech   = (unsigned*)(ws + WS_MECH);
    unsigned* probe  = (unsigned*)(ws + WS_PROBE);
    float*    xTp    = (float*)(ws + WS_XT);
    float*    hlast  = (float*)(ws + WS_HLAST);
    _Float16* h1Fhi  = (_Float16*)(ws + WS_H1HI);
    _Float16* h1Flo  = (_Float16*)(ws + WS_H1LO);

    hipMemsetAsync(ws, 0, WS_ZEROL, stream);
    xt_kernel<<<(B_ * T_ * 3 + 255) / 256, 256, 0, stream>>>(x, xTp);
    fused_slstm<<<NC_ * P_, NW_ * 64, 0, stream>>>(xTp, W0, R0, b0, W1, R1, b1,
                                                   hexFhi, hexFlo, flagR, flagX,
                                                   xccb, mech, probe,
                                                   h1Fhi, h1Flo, hlast);
    fc_kernel<<<B_, 64, 0, stream>>>(hlast, fcw, fcb, out);
}